// Round 4
// baseline (680.609 us; speedup 1.0000x reference)
//
#include <hip/hip_runtime.h>
#include <math.h>

#define B_DIM 2048
#define M_DIM 4096
#define N_DIM 64
#define S_DIM 64
#define EPS_TOTAL 0.001f

// Single fused kernel. Block = 256 threads = 4 waves; wave w owns b-row
// blockIdx.x*4 + w. m processed in chunks of 64 (lane = m - m0); n staged
// to LDS in halves of 32.
// NOTE: harness compares only Re(T) (complex64 ref astype(float32)):
// d_out is 131072 floats = (B, S) real part. Writing 2*out_size faulted.
__global__ __launch_bounds__(256) void cpsf_fused(
    const float* __restrict__ z_re, const float* __restrict__ z_im,
    const float* __restrict__ d_re, const float* __restrict__ d_im,
    const float* __restrict__ zj_re, const float* __restrict__ zj_im,
    const float* __restrict__ dj_re, const float* __restrict__ dj_im,
    const float* __restrict__ That_re,
    const float* __restrict__ alpha, const float* __restrict__ sig_par,
    const float* __restrict__ sig_perp, float* __restrict__ out) {
  __shared__ float2 mf[4][16][65];  // [feat][n-pair within half][m], padded
  __shared__ float zfs[4][4][64];   // [wave][feat][n] (z_re,z_im,d_re,d_im)
  __shared__ float wgt_s[4][64];    // [wave][m within chunk]

  const int tid = threadIdx.x;
  const int w = tid >> 6, lane = tid & 63;
  const int b = blockIdx.x * 4 + w;

  // Stage per-b features (scalar loads, coalesced) + |z|^2, |d|^2 reduce.
  const float vzr = z_re[b * N_DIM + lane];
  const float vzi = z_im[b * N_DIM + lane];
  const float vdr = d_re[b * N_DIM + lane];
  const float vdi = d_im[b * N_DIM + lane];
  zfs[w][0][lane] = vzr;
  zfs[w][1][lane] = vzi;
  zfs[w][2][lane] = vdr;
  zfs[w][3][lane] = vdi;
  float z2 = vzr * vzr + vzi * vzi;
  float dsq = vdr * vdr + vdi * vdi;
#pragma unroll
  for (int off = 1; off < 64; off <<= 1) {
    z2 += __shfl_xor(z2, off);
    dsq += __shfl_xor(dsq, off);
  }

  // Quadrature nodes/weights as local literals (unrolled -> immediates).
  const float TQ[8] = {0.019855071751231885f, 0.101666761293186630f,
                       0.237233795041835510f, 0.408282678752175100f,
                       0.591717321247824900f, 0.762766204958164500f,
                       0.898333238706813370f, 0.980144928248768120f};
  const float WQ[8] = {0.050614268145188130f, 0.111190517226687240f,
                       0.156853322938943640f, 0.181341891689180990f,
                       0.181341891689180990f, 0.156853322938943640f,
                       0.111190517226687240f, 0.050614268145188130f};

  float Tr = 0.f;

  for (int m0 = 0; m0 < M_DIM; m0 += 64) {
    float ipr = 0.f, ipi = 0.f, zd = 0.f, ad = 0.f;
    float dd2 = 0.f, c1r = 0.f, c1i = 0.f, zj2 = 0.f;

    for (int sub = 0; sub < 2; ++sub) {
      __syncthreads();  // all waves done reading mf from previous tile
      // Stage 4 feats x 64 m x 32 n (transposed to [np][m]) via scalar
      // global loads; i>>2 selects the feature at compile time.
#pragma unroll
      for (int i = 0; i < 16; ++i) {
        const float* src = ((i >> 2) == 0) ? dj_re
                         : ((i >> 2) == 1) ? dj_im
                         : ((i >> 2) == 2) ? zj_re : zj_im;
        const int rem = tid + (i & 3) * 256;    // [0,1024)
        const int np = rem & 15, mm = rem >> 4; // np<16, mm<64
        const int g = (m0 + mm) * N_DIM + sub * 32 + 2 * np;
        mf[i >> 2][np][mm] = make_float2(src[g], src[g + 1]);
      }
      __syncthreads();

      const float* zr_p = &zfs[w][0][sub * 32];
      const float* zi_p = &zfs[w][1][sub * 32];
      const float* dr_p = &zfs[w][2][sub * 32];
      const float* di_p = &zfs[w][3][sub * 32];
#pragma unroll 4
      for (int np = 0; np < 16; ++np) {
        const float2 A = mf[0][np][lane];   // dj_re pair
        const float2 Bv = mf[1][np][lane];  // dj_im pair
        const float2 C = mf[2][np][lane];   // zj_re pair
        const float2 D = mf[3][np][lane];   // zj_im pair
        const float zr0 = zr_p[2 * np], zr1 = zr_p[2 * np + 1];
        const float zi0 = zi_p[2 * np], zi1 = zi_p[2 * np + 1];
        const float dr0 = dr_p[2 * np], dr1 = dr_p[2 * np + 1];
        const float di0 = di_p[2 * np], di1 = di_p[2 * np + 1];
        // b-dependent dots
        ipr = fmaf(A.x, zr0, ipr);  ipr = fmaf(A.y, zr1, ipr);
        ipr = fmaf(Bv.x, zi0, ipr); ipr = fmaf(Bv.y, zi1, ipr);
        ipi = fmaf(A.x, zi0, ipi);  ipi = fmaf(A.y, zi1, ipi);
        ipi = fmaf(-Bv.x, zr0, ipi); ipi = fmaf(-Bv.y, zr1, ipi);
        zd = fmaf(C.x, zr0, zd);    zd = fmaf(C.y, zr1, zd);
        zd = fmaf(D.x, zi0, zd);    zd = fmaf(D.y, zi1, zd);
        ad = fmaf(A.x, dr0, ad);    ad = fmaf(A.y, dr1, ad);
        ad = fmaf(Bv.x, di0, ad);   ad = fmaf(Bv.y, di1, ad);
        // per-m constants (b-independent, recomputed per block)
        dd2 = fmaf(A.x, A.x, dd2);   dd2 = fmaf(A.y, A.y, dd2);
        dd2 = fmaf(Bv.x, Bv.x, dd2); dd2 = fmaf(Bv.y, Bv.y, dd2);
        c1r = fmaf(A.x, C.x, c1r);   c1r = fmaf(A.y, C.y, c1r);
        c1r = fmaf(Bv.x, D.x, c1r);  c1r = fmaf(Bv.y, D.y, c1r);
        c1i = fmaf(A.x, D.x, c1i);   c1i = fmaf(A.y, D.y, c1i);
        c1i = fmaf(-Bv.x, C.x, c1i); c1i = fmaf(-Bv.y, C.y, c1i);
        zj2 = fmaf(C.x, C.x, zj2);   zj2 = fmaf(C.y, C.y, zj2);
        zj2 = fmaf(D.x, D.x, zj2);   zj2 = fmaf(D.y, D.y, zj2);
      }
    }

    // Scalar tail + quadrature for this lane's m.
    const int m = m0 + lane;
    const float sp = sig_par[m], so = sig_perp[m], al = alpha[m];
    const float nsp = -0.5f / fmaf(sp, sp, EPS_TOTAL);
    const float nso = -0.5f / fmaf(so, so, EPS_TOTAL);
    const float ipr2 = ipr - c1r;
    const float ipi2 = ipi - c1i;
    const float q0 = z2 - 2.f * zd + zj2;
    const float dbase = (dsq - 2.f * ad + dd2) * nso;  // -dist_d/(2 so2)
    const float ii2 = ipi2 * ipi2;
    const float e2 = 2.f * ipr2;
    float acc = 0.f;
#pragma unroll
    for (int k = 0; k < 8; ++k) {
      const float tk = TQ[k];
      const float wr = fmaf(-tk, dd2, ipr2);
      const float qp = fmaf(wr, wr, ii2);
      const float q2 = fmaf(tk, fmaf(tk, dd2, -e2), q0);
      const float qperp = fmaxf(q2 - qp, 0.f);
      const float arg = fmaf(qp, nsp, fmaf(qperp, nso, dbase));
      acc = fmaf(WQ[k], __expf(arg), acc);
    }
    wgt_s[w][lane] = al * acc;  // wave-local write, wave-local reads below

    // Re(T) accumulation: lane = s. (Harness compares real part only.)
    const float* tre_p = That_re + (size_t)m0 * S_DIM + lane;
    const float* wrow = &wgt_s[w][0];
#pragma unroll 8
    for (int mm = 0; mm < 64; ++mm) {
      Tr = fmaf(wrow[mm], tre_p[mm * S_DIM], Tr);  // LDS broadcast
    }
  }

  // Real-part output: exactly out_size = B*S floats.
  out[(size_t)b * S_DIM + lane] = Tr;
}

extern "C" void kernel_launch(void* const* d_in, const int* in_sizes, int n_in,
                              void* d_out, int out_size, void* d_ws,
                              size_t ws_size, hipStream_t stream) {
  const float* z_re = (const float*)d_in[0];
  const float* z_im = (const float*)d_in[1];
  const float* d_re = (const float*)d_in[2];
  const float* d_im = (const float*)d_in[3];
  const float* zj_re = (const float*)d_in[4];
  const float* zj_im = (const float*)d_in[5];
  const float* dj_re = (const float*)d_in[6];
  const float* dj_im = (const float*)d_in[7];
  const float* That_re = (const float*)d_in[8];
  const float* alpha = (const float*)d_in[10];
  const float* sig_par = (const float*)d_in[11];
  const float* sig_perp = (const float*)d_in[12];

  cpsf_fused<<<dim3(B_DIM / 4), dim3(256), 0, stream>>>(
      z_re, z_im, d_re, d_im, zj_re, zj_im, dj_re, dj_im, That_re,
      alpha, sig_par, sig_perp, (float*)d_out);
}

// Round 5
// 132.789 us; speedup vs baseline: 5.1255x; 5.1255x over previous
//
#include <hip/hip_runtime.h>
#include <math.h>

#define B_DIM 2048
#define M_DIM 4096
#define N_DIM 64
#define S_DIM 64
#define EPS_TOTAL 0.001f
#define MSPLIT 8
#define MR (M_DIM / MSPLIT)  // 512 m per block
#define BTILE 64             // b per block

typedef __attribute__((ext_vector_type(8))) short short8v;
typedef __attribute__((ext_vector_type(4))) float float4v;

#define MFMA(a, b, c) __builtin_amdgcn_mfma_f32_16x16x32_bf16(a, b, c, 0, 0, 0)

// Module-owned buffers (crash root-cause was d_out overwrite, not globals).
// wfrag: [mtile 256][kstep 4][mat 3][split 2][lane 64][8 bf16]  (25.2 MB)
__device__ unsigned short wfrag_g[256 * 4 * 3 * 2 * 64 * 8];
__device__ float mc_g[M_DIM * 8];    // c1r,c1i,dd2,zj2,nsp,nso,alpha,pad
__device__ float bsq_g[B_DIM * 2];   // z2, dsq
__device__ float part_g[MSPLIT * B_DIM * S_DIM];  // 4 MB partial T

__device__ inline unsigned short f32_bf16(float x) {
  unsigned int u = __float_as_uint(x);
  unsigned int r = (u + 0x7fffu + ((u >> 16) & 1u)) >> 16;  // RNE
  return (unsigned short)r;
}
__device__ inline float bf16_f32(unsigned short h) {
  return __uint_as_float(((unsigned int)h) << 16);
}

// ---------------- P1: W fragments (bf16 hi/lo, mfma B-layout) -------------
__global__ __launch_bounds__(256) void build_wfrag(
    const float* __restrict__ zj_re, const float* __restrict__ zj_im,
    const float* __restrict__ dj_re, const float* __restrict__ dj_im) {
  const int gid = blockIdx.x * 256 + threadIdx.x;  // [0, 393216)
  const int lane = gid & 63;
  const int rest = gid >> 6;  // [0, 6144) = [mtile][kstep][mat][split]
  const int split = rest & 1;
  int tmp = rest >> 1;
  const int mat = tmp % 3;
  tmp /= 3;
  const int kstep = tmp & 3;
  const int mtile = tmp >> 2;
  const int m = mtile * 16 + (lane & 15);
  const int g = lane >> 4;
  unsigned short o[8];
#pragma unroll
  for (int e = 0; e < 8; ++e) {
    const int k = kstep * 32 + ((e >> 2) << 4) + (g << 2) + (e & 3);
    float v;
    if (k < 64) {  // pairs with z_re / d_re
      v = (mat == 0) ? dj_re[m * 64 + k]
        : (mat == 1) ? -dj_im[m * 64 + k]
                     : zj_re[m * 64 + k];
    } else {       // pairs with z_im / d_im
      const int kk = k - 64;
      v = (mat == 0) ? dj_im[m * 64 + kk]
        : (mat == 1) ? dj_re[m * 64 + kk]
                     : zj_im[m * 64 + kk];
    }
    const unsigned short h = f32_bf16(v);
    o[e] = split ? f32_bf16(v - bf16_f32(h)) : h;
  }
  uint4 u;
  u.x = (unsigned)o[0] | ((unsigned)o[1] << 16);
  u.y = (unsigned)o[2] | ((unsigned)o[3] << 16);
  u.z = (unsigned)o[4] | ((unsigned)o[5] << 16);
  u.w = (unsigned)o[6] | ((unsigned)o[7] << 16);
  *(uint4*)(wfrag_g + (size_t)gid * 8) = u;
}

// ---------------- P2: per-m constants ------------------------------------
__global__ __launch_bounds__(256) void build_mconst(
    const float* __restrict__ dj_re, const float* __restrict__ dj_im,
    const float* __restrict__ zj_re, const float* __restrict__ zj_im,
    const float* __restrict__ alpha, const float* __restrict__ sig_par,
    const float* __restrict__ sig_perp) {
  const int w = threadIdx.x >> 6, lane = threadIdx.x & 63;
  const int m = blockIdx.x * 4 + w;
  const int idx = m * N_DIM + lane;
  const float djr = dj_re[idx], dji = dj_im[idx];
  const float zjr = zj_re[idx], zji = zj_im[idx];
  float dd2 = djr * djr + dji * dji;
  float c1r = djr * zjr + dji * zji;   // Re(conj(dj)*zj)
  float c1i = djr * zji - dji * zjr;   // Im(conj(dj)*zj)
  float zj2 = zjr * zjr + zji * zji;
#pragma unroll
  for (int off = 1; off < 64; off <<= 1) {
    dd2 += __shfl_xor(dd2, off);
    c1r += __shfl_xor(c1r, off);
    c1i += __shfl_xor(c1i, off);
    zj2 += __shfl_xor(zj2, off);
  }
  if (lane == 0) {
    const float sp = sig_par[m], so = sig_perp[m];
    float* o = mc_g + m * 8;
    o[0] = c1r;
    o[1] = c1i;
    o[2] = dd2;
    o[3] = zj2;
    o[4] = -0.5f / fmaf(sp, sp, EPS_TOTAL);
    o[5] = -0.5f / fmaf(so, so, EPS_TOTAL);
    o[6] = alpha[m];
    o[7] = 0.f;
  }
}

// ---------------- P3: per-b squared norms --------------------------------
__global__ __launch_bounds__(256) void build_bsq(
    const float* __restrict__ z_re, const float* __restrict__ z_im,
    const float* __restrict__ d_re, const float* __restrict__ d_im) {
  const int w = threadIdx.x >> 6, lane = threadIdx.x & 63;
  const int b = blockIdx.x * 4 + w;
  const int idx = b * N_DIM + lane;
  const float zr = z_re[idx], zi = z_im[idx];
  const float dr = d_re[idx], di = d_im[idx];
  float z2 = zr * zr + zi * zi;
  float dsq = dr * dr + di * di;
#pragma unroll
  for (int off = 1; off < 64; off <<= 1) {
    z2 += __shfl_xor(z2, off);
    dsq += __shfl_xor(dsq, off);
  }
  if (lane == 0) {
    bsq_g[b * 2] = z2;
    bsq_g[b * 2 + 1] = dsq;
  }
}

// ---------------- main: MFMA GEMM + quadrature + That --------------------
__device__ inline void stage6(const unsigned short* __restrict__ src,
                              unsigned short* dst) {
#pragma unroll
  for (int j = 0; j < 6; ++j)
    __builtin_amdgcn_global_load_lds(
        (const __attribute__((address_space(1))) void*)(src + j * 512),
        (__attribute__((address_space(3))) void*)(dst + j * 512), 16, 0, 0);
}

__global__ __launch_bounds__(256) void cpsf_mfma(
    const float* __restrict__ z_re, const float* __restrict__ z_im,
    const float* __restrict__ d_re, const float* __restrict__ d_im,
    const float* __restrict__ That_re) {
  // LDS: 2*49152 + 16640 + 2304 + 512 = 117760 B -> 1 block/CU
  __shared__ __align__(16) unsigned short wlds[2][24576];
  __shared__ float wgt_lds[64][65];
  __shared__ float mc_lds[64][9];
  __shared__ float bsq_lds[64][2];

  const int tid = threadIdx.x;
  const int w = tid >> 6, lane = tid & 63;
  const int bt = blockIdx.x >> 3;   // 32 b-tiles
  const int ms = blockIdx.x & 7;    // 8 m-splits
  const int b0 = bt * BTILE;
  const int wu = __builtin_amdgcn_readfirstlane(w);

  if (tid < 128)
    bsq_lds[tid >> 1][tid & 1] = bsq_g[(b0 + (tid >> 1)) * 2 + (tid & 1)];

  // ---- A fragments (16 b per wave, K=128, A1=z, A2=d, hi/lo split) ----
  const int bb = b0 + w * 16 + (lane & 15);
  const int g = lane >> 4;
  short8v A1h[4], A1l[4], A2h[4], A2l[4];
#pragma unroll
  for (int ks = 0; ks < 4; ++ks) {
#pragma unroll
    for (int e = 0; e < 8; ++e) {
      const int k = ks * 32 + ((e >> 2) << 4) + (g << 2) + (e & 3);
      float a1, a2;
      if (k < 64) {
        a1 = z_re[bb * 64 + k];
        a2 = d_re[bb * 64 + k];
      } else {
        a1 = z_im[bb * 64 + k - 64];
        a2 = d_im[bb * 64 + k - 64];
      }
      const unsigned short h1 = f32_bf16(a1);
      A1h[ks][e] = (short)h1;
      A1l[ks][e] = (short)f32_bf16(a1 - bf16_f32(h1));
      const unsigned short h2 = f32_bf16(a2);
      A2h[ks][e] = (short)h2;
      A2l[ks][e] = (short)f32_bf16(a2 - bf16_f32(h2));
    }
  }

  const float TQ[8] = {0.019855071751231885f, 0.101666761293186630f,
                       0.237233795041835510f, 0.408282678752175100f,
                       0.591717321247824900f, 0.762766204958164500f,
                       0.898333238706813370f, 0.980144928248768120f};
  const float WQ[8] = {0.050614268145188130f, 0.111190517226687240f,
                       0.156853322938943640f, 0.181341891689180990f,
                       0.181341891689180990f, 0.156853322938943640f,
                       0.111190517226687240f, 0.050614268145188130f};

  float Tr[16];
#pragma unroll
  for (int i = 0; i < 16; ++i) Tr[i] = 0.f;

  for (int ci = 0; ci < 8; ++ci) {
    const int m0 = ms * MR + ci * 64;
    const int mtile0 = m0 >> 4;

    __syncthreads();  // prior chunk fully done with mc_lds / wlds

    // stage per-m constants (512 floats)
    {
      const int r = tid >> 2, c = (tid & 3) * 2;
      mc_lds[r][c] = mc_g[(m0 + r) * 8 + c];
      mc_lds[r][c + 1] = mc_g[(m0 + r) * 8 + c + 1];
    }
    // stage W kstep 0 -> buf 0 (each wave stages its m-subtile)
    stage6(wfrag_g + (size_t)(((mtile0 + wu) * 4 + 0) * 3072 + lane * 8),
           &wlds[0][wu * 3072]);

    float4v acc[4][4];
#pragma unroll
    for (int mt = 0; mt < 4; ++mt)
#pragma unroll
      for (int dd = 0; dd < 4; ++dd) acc[mt][dd] = (float4v){0.f, 0.f, 0.f, 0.f};

    int buf = 0;
#pragma unroll
    for (int ks = 0; ks < 4; ++ks) {
      __syncthreads();  // staged W ready; previous buffer free
      if (ks < 3)
        stage6(wfrag_g +
                   (size_t)(((mtile0 + wu) * 4 + (ks + 1)) * 3072 + lane * 8),
               &wlds[buf ^ 1][wu * 3072]);
      const short8v a1h = A1h[ks], a1l = A1l[ks];
      const short8v a2h = A2h[ks], a2l = A2l[ks];
#pragma unroll
      for (int mt = 0; mt < 4; ++mt) {
        const int so = mt * 3072 + lane * 8;
        const short8v w1h = *(const short8v*)&wlds[buf][so + 0 * 512];
        const short8v w1l = *(const short8v*)&wlds[buf][so + 1 * 512];
        const short8v w2h = *(const short8v*)&wlds[buf][so + 2 * 512];
        const short8v w2l = *(const short8v*)&wlds[buf][so + 3 * 512];
        const short8v w3h = *(const short8v*)&wlds[buf][so + 4 * 512];
        const short8v w3l = *(const short8v*)&wlds[buf][so + 5 * 512];
        acc[mt][0] = MFMA(a1h, w1h, acc[mt][0]);
        acc[mt][0] = MFMA(a1h, w1l, acc[mt][0]);
        acc[mt][0] = MFMA(a1l, w1h, acc[mt][0]);
        acc[mt][1] = MFMA(a1h, w2h, acc[mt][1]);
        acc[mt][1] = MFMA(a1h, w2l, acc[mt][1]);
        acc[mt][1] = MFMA(a1l, w2h, acc[mt][1]);
        acc[mt][2] = MFMA(a1h, w3h, acc[mt][2]);
        acc[mt][2] = MFMA(a1h, w3l, acc[mt][2]);
        acc[mt][2] = MFMA(a1l, w3h, acc[mt][2]);
        acc[mt][3] = MFMA(a2h, w1h, acc[mt][3]);
        acc[mt][3] = MFMA(a2h, w1l, acc[mt][3]);
        acc[mt][3] = MFMA(a2l, w1h, acc[mt][3]);
      }
      buf ^= 1;
    }

    // ---- quadrature on accumulators (r4-proven numerics) ----
#pragma unroll
    for (int mt = 0; mt < 4; ++mt) {
      const int mloc = mt * 16 + (lane & 15);
      const float c1r = mc_lds[mloc][0], c1i = mc_lds[mloc][1];
      const float dd2 = mc_lds[mloc][2], zj2 = mc_lds[mloc][3];
      const float nsp = mc_lds[mloc][4], nso = mc_lds[mloc][5];
      const float al = mc_lds[mloc][6];
#pragma unroll
      for (int r = 0; r < 4; ++r) {
        const int bloc = w * 16 + (lane >> 4) * 4 + r;  // D row = 4g + r
        const float z2v = bsq_lds[bloc][0], dsqv = bsq_lds[bloc][1];
        const float ipr2 = acc[mt][0][r] - c1r;
        const float ipi2 = acc[mt][1][r] - c1i;
        const float zd = acc[mt][2][r];
        const float ad = acc[mt][3][r];
        const float q0 = z2v - 2.f * zd + zj2;
        const float dbase = (dsqv - 2.f * ad + dd2) * nso;
        const float ii2 = ipi2 * ipi2;
        const float e2 = 2.f * ipr2;
        float qacc = 0.f;
#pragma unroll
        for (int kq = 0; kq < 8; ++kq) {
          const float tk = TQ[kq];
          const float wr = fmaf(-tk, dd2, ipr2);
          const float qp = fmaf(wr, wr, ii2);
          const float q2 = fmaf(tk, fmaf(tk, dd2, -e2), q0);
          const float qperp = fmaxf(q2 - qp, 0.f);
          const float arg = fmaf(qp, nsp, fmaf(qperp, nso, dbase));
          qacc = fmaf(WQ[kq], __expf(arg), qacc);
        }
        wgt_lds[bloc][mloc] = al * qacc;  // wave-private rows
      }
    }

    // ---- That accumulation (wave-private wgt rows; no barrier needed) ----
#pragma unroll 4
    for (int mm = 0; mm < 64; ++mm) {
      const float th = That_re[(size_t)(m0 + mm) * S_DIM + lane];
#pragma unroll
      for (int bl = 0; bl < 16; ++bl)
        Tr[bl] = fmaf(wgt_lds[w * 16 + bl][mm], th, Tr[bl]);
    }
  }

  // partial T for this m-split
#pragma unroll
  for (int bl = 0; bl < 16; ++bl)
    part_g[((size_t)ms * B_DIM + (b0 + w * 16 + bl)) * S_DIM + lane] = Tr[bl];
}

// ---------------- reduce partials ----------------------------------------
__global__ __launch_bounds__(256) void reduce_parts(float* __restrict__ out) {
  const int i = blockIdx.x * 256 + threadIdx.x;  // [0, 131072)
  float s = 0.f;
#pragma unroll
  for (int p = 0; p < MSPLIT; ++p) s += part_g[(size_t)p * B_DIM * S_DIM + i];
  out[i] = s;
}

extern "C" void kernel_launch(void* const* d_in, const int* in_sizes, int n_in,
                              void* d_out, int out_size, void* d_ws,
                              size_t ws_size, hipStream_t stream) {
  const float* z_re = (const float*)d_in[0];
  const float* z_im = (const float*)d_in[1];
  const float* d_re = (const float*)d_in[2];
  const float* d_im = (const float*)d_in[3];
  const float* zj_re = (const float*)d_in[4];
  const float* zj_im = (const float*)d_in[5];
  const float* dj_re = (const float*)d_in[6];
  const float* dj_im = (const float*)d_in[7];
  const float* That_re = (const float*)d_in[8];
  const float* alpha = (const float*)d_in[10];
  const float* sig_par = (const float*)d_in[11];
  const float* sig_perp = (const float*)d_in[12];

  build_wfrag<<<dim3(1536), dim3(256), 0, stream>>>(zj_re, zj_im, dj_re, dj_im);
  build_mconst<<<dim3(M_DIM / 4), dim3(256), 0, stream>>>(
      dj_re, dj_im, zj_re, zj_im, alpha, sig_par, sig_perp);
  build_bsq<<<dim3(B_DIM / 4), dim3(256), 0, stream>>>(z_re, z_im, d_re, d_im);
  cpsf_mfma<<<dim3((B_DIM / BTILE) * MSPLIT), dim3(256), 0, stream>>>(
      z_re, z_im, d_re, d_im, That_re);
  reduce_parts<<<dim3(B_DIM * S_DIM / 256), dim3(256), 0, stream>>>(
      (float*)d_out);
}

// Round 6
// 106.111 us; speedup vs baseline: 6.4141x; 1.2514x over previous
//
#include <hip/hip_runtime.h>
#include <math.h>

#define B_DIM 2048
#define M_DIM 4096
#define N_DIM 64
#define S_DIM 64
#define EPS_TOTAL 0.001f
#define MSPLIT 16
#define MR (M_DIM / MSPLIT)  // 256 m per block
#define BTILE 64             // b per block

typedef __attribute__((ext_vector_type(8))) short short8v;
typedef __attribute__((ext_vector_type(4))) float float4v;

#define MFMA(a, b, c) __builtin_amdgcn_mfma_f32_16x16x32_bf16(a, b, c, 0, 0, 0)

// Module-owned buffers.
// wfrag: [mtile 256][kstep 4][mat 3][split 2][lane 64][8 bf16]  (25.2 MB)
__device__ unsigned short wfrag_g[256 * 4 * 3 * 2 * 64 * 8];
// tfrag: [mchunk 64][ct 4][ks2 2][split 2][lane 64][8 bf16]     (1 MB)
__device__ unsigned short tfrag_g[64 * 4 * 2 * 2 * 64 * 8];
__device__ float mc_g[M_DIM * 8];    // c1r,c1i,dd2,zj2,nsp,nso,alpha,pad
__device__ float bsq_g[B_DIM * 2];   // z2, dsq
__device__ float part_g[MSPLIT * B_DIM * S_DIM];  // 8 MB partial T

__device__ inline unsigned short f32_bf16(float x) {
  unsigned int u = __float_as_uint(x);
  unsigned int r = (u + 0x7fffu + ((u >> 16) & 1u)) >> 16;  // RNE
  return (unsigned short)r;
}
__device__ inline float bf16_f32(unsigned short h) {
  return __uint_as_float(((unsigned int)h) << 16);
}

// ---------------- P1: W fragments (bf16 hi/lo, mfma B-layout) -------------
__global__ __launch_bounds__(256) void build_wfrag(
    const float* __restrict__ zj_re, const float* __restrict__ zj_im,
    const float* __restrict__ dj_re, const float* __restrict__ dj_im) {
  const int gid = blockIdx.x * 256 + threadIdx.x;  // [0, 393216)
  const int lane = gid & 63;
  const int rest = gid >> 6;  // [mtile][kstep][mat][split]
  const int split = rest & 1;
  int tmp = rest >> 1;
  const int mat = tmp % 3;
  tmp /= 3;
  const int kstep = tmp & 3;
  const int mtile = tmp >> 2;
  const int m = mtile * 16 + (lane & 15);
  const int g = lane >> 4;
  unsigned short o[8];
#pragma unroll
  for (int e = 0; e < 8; ++e) {
    const int k = kstep * 32 + ((e >> 2) << 4) + (g << 2) + (e & 3);
    float v;
    if (k < 64) {  // pairs with z_re / d_re
      v = (mat == 0) ? dj_re[m * 64 + k]
        : (mat == 1) ? -dj_im[m * 64 + k]
                     : zj_re[m * 64 + k];
    } else {       // pairs with z_im / d_im
      const int kk = k - 64;
      v = (mat == 0) ? dj_im[m * 64 + kk]
        : (mat == 1) ? dj_re[m * 64 + kk]
                     : zj_im[m * 64 + kk];
    }
    const unsigned short h = f32_bf16(v);
    o[e] = split ? f32_bf16(v - bf16_f32(h)) : h;
  }
  uint4 u;
  u.x = (unsigned)o[0] | ((unsigned)o[1] << 16);
  u.y = (unsigned)o[2] | ((unsigned)o[3] << 16);
  u.z = (unsigned)o[4] | ((unsigned)o[5] << 16);
  u.w = (unsigned)o[6] | ((unsigned)o[7] << 16);
  *(uint4*)(wfrag_g + (size_t)gid * 8) = u;
}

// ---------------- P1b: That fragments (bf16 hi/lo, mfma B-layout) ---------
__global__ __launch_bounds__(256) void build_tfrag(
    const float* __restrict__ That_re) {
  const int gid = blockIdx.x * 256 + threadIdx.x;  // [0, 65536)
  const int lane = gid & 63;
  const int rest = gid >> 6;  // [mchunk][ct][ks2][split]
  const int split = rest & 1;
  const int ks2 = (rest >> 1) & 1;
  const int ct = (rest >> 2) & 3;
  const int mchunk = rest >> 4;
  const int s = ct * 16 + (lane & 15);
  const int g = lane >> 4;
  unsigned short o[8];
#pragma unroll
  for (int e = 0; e < 8; ++e) {
    const int k = ks2 * 32 + ((e >> 2) << 4) + (g << 2) + (e & 3);
    const float v = That_re[(size_t)(mchunk * 64 + k) * S_DIM + s];
    const unsigned short h = f32_bf16(v);
    o[e] = split ? f32_bf16(v - bf16_f32(h)) : h;
  }
  uint4 u;
  u.x = (unsigned)o[0] | ((unsigned)o[1] << 16);
  u.y = (unsigned)o[2] | ((unsigned)o[3] << 16);
  u.z = (unsigned)o[4] | ((unsigned)o[5] << 16);
  u.w = (unsigned)o[6] | ((unsigned)o[7] << 16);
  *(uint4*)(tfrag_g + (size_t)gid * 8) = u;
}

// ---------------- P2: per-m constants ------------------------------------
__global__ __launch_bounds__(256) void build_mconst(
    const float* __restrict__ dj_re, const float* __restrict__ dj_im,
    const float* __restrict__ zj_re, const float* __restrict__ zj_im,
    const float* __restrict__ alpha, const float* __restrict__ sig_par,
    const float* __restrict__ sig_perp) {
  const int w = threadIdx.x >> 6, lane = threadIdx.x & 63;
  const int m = blockIdx.x * 4 + w;
  const int idx = m * N_DIM + lane;
  const float djr = dj_re[idx], dji = dj_im[idx];
  const float zjr = zj_re[idx], zji = zj_im[idx];
  float dd2 = djr * djr + dji * dji;
  float c1r = djr * zjr + dji * zji;
  float c1i = djr * zji - dji * zjr;
  float zj2 = zjr * zjr + zji * zji;
#pragma unroll
  for (int off = 1; off < 64; off <<= 1) {
    dd2 += __shfl_xor(dd2, off);
    c1r += __shfl_xor(c1r, off);
    c1i += __shfl_xor(c1i, off);
    zj2 += __shfl_xor(zj2, off);
  }
  if (lane == 0) {
    const float sp = sig_par[m], so = sig_perp[m];
    float* o = mc_g + m * 8;
    o[0] = c1r;
    o[1] = c1i;
    o[2] = dd2;
    o[3] = zj2;
    o[4] = -0.5f / fmaf(sp, sp, EPS_TOTAL);
    o[5] = -0.5f / fmaf(so, so, EPS_TOTAL);
    o[6] = alpha[m];
    o[7] = 0.f;
  }
}

// ---------------- P3: per-b squared norms --------------------------------
__global__ __launch_bounds__(256) void build_bsq(
    const float* __restrict__ z_re, const float* __restrict__ z_im,
    const float* __restrict__ d_re, const float* __restrict__ d_im) {
  const int w = threadIdx.x >> 6, lane = threadIdx.x & 63;
  const int b = blockIdx.x * 4 + w;
  const int idx = b * N_DIM + lane;
  const float zr = z_re[idx], zi = z_im[idx];
  const float dr = d_re[idx], di = d_im[idx];
  float z2 = zr * zr + zi * zi;
  float dsq = dr * dr + di * di;
#pragma unroll
  for (int off = 1; off < 64; off <<= 1) {
    z2 += __shfl_xor(z2, off);
    dsq += __shfl_xor(dsq, off);
  }
  if (lane == 0) {
    bsq_g[b * 2] = z2;
    bsq_g[b * 2 + 1] = dsq;
  }
}

// ---------------- main: MFMA GEMM + quadrature + That (MFMA) -------------
__device__ inline void stage6(const unsigned short* __restrict__ src,
                              unsigned short* dst) {
#pragma unroll
  for (int j = 0; j < 6; ++j)
    __builtin_amdgcn_global_load_lds(
        (const __attribute__((address_space(1))) void*)(src + j * 512),
        (__attribute__((address_space(3))) void*)(dst + j * 512), 16, 0, 0);
}

__global__ __launch_bounds__(256) void cpsf_mfma(
    const float* __restrict__ z_re, const float* __restrict__ z_im,
    const float* __restrict__ d_re, const float* __restrict__ d_im) {
  // LDS: 49152 (wlds) + 17408 (wgt hi/lo) + 2304 + 512 = 69376 B -> 2 blk/CU
  __shared__ __align__(16) unsigned short wlds[2][12288];
  __shared__ __align__(16) unsigned short wgt_hi[64][68];
  __shared__ __align__(16) unsigned short wgt_lo[64][68];
  __shared__ float mc_lds[64][9];
  __shared__ float bsq_lds[64][2];

  const int tid = threadIdx.x;
  const int w = tid >> 6, lane = tid & 63;
  const int bt = blockIdx.x >> 4;   // 32 b-tiles
  const int ms = blockIdx.x & 15;   // 16 m-splits
  const int b0 = bt * BTILE;
  const int wu = __builtin_amdgcn_readfirstlane(w);

  if (tid < 128)
    bsq_lds[tid >> 1][tid & 1] = bsq_g[(b0 + (tid >> 1)) * 2 + (tid & 1)];

  // ---- A fragments (16 b per wave, K=128, A1=z, A2=d, hi/lo split) ----
  const int bb = b0 + w * 16 + (lane & 15);
  const int g = lane >> 4;
  short8v A1h[4], A1l[4], A2h[4], A2l[4];
#pragma unroll
  for (int ks = 0; ks < 4; ++ks) {
#pragma unroll
    for (int e = 0; e < 8; ++e) {
      const int k = ks * 32 + ((e >> 2) << 4) + (g << 2) + (e & 3);
      float a1, a2;
      if (k < 64) {
        a1 = z_re[bb * 64 + k];
        a2 = d_re[bb * 64 + k];
      } else {
        a1 = z_im[bb * 64 + k - 64];
        a2 = d_im[bb * 64 + k - 64];
      }
      const unsigned short h1 = f32_bf16(a1);
      A1h[ks][e] = (short)h1;
      A1l[ks][e] = (short)f32_bf16(a1 - bf16_f32(h1));
      const unsigned short h2 = f32_bf16(a2);
      A2h[ks][e] = (short)h2;
      A2l[ks][e] = (short)f32_bf16(a2 - bf16_f32(h2));
    }
  }

  const float TQ[8] = {0.019855071751231885f, 0.101666761293186630f,
                       0.237233795041835510f, 0.408282678752175100f,
                       0.591717321247824900f, 0.762766204958164500f,
                       0.898333238706813370f, 0.980144928248768120f};
  const float WQ[8] = {0.050614268145188130f, 0.111190517226687240f,
                       0.156853322938943640f, 0.181341891689180990f,
                       0.181341891689180990f, 0.156853322938943640f,
                       0.111190517226687240f, 0.050614268145188130f};

  float4v Tacc[4];
#pragma unroll
  for (int i = 0; i < 4; ++i) Tacc[i] = (float4v){0.f, 0.f, 0.f, 0.f};

  for (int ci = 0; ci < MR / 64; ++ci) {
    const int m0 = ms * MR + ci * 64;
    const int mtile0 = m0 >> 4;

    __syncthreads();  // prior chunk fully done with mc_lds / wlds / wgt

    // stage per-m constants (512 floats)
    {
      const int r = tid >> 2, c = (tid & 3) * 2;
      mc_lds[r][c] = mc_g[(m0 + r) * 8 + c];
      mc_lds[r][c + 1] = mc_g[(m0 + r) * 8 + c + 1];
    }
    // stage W kstep 0 -> buf 0 (each wave stages its m-subtile)
    stage6(wfrag_g + (size_t)(((mtile0 + wu) * 4 + 0) * 3072 + lane * 8),
           &wlds[0][wu * 3072]);

    float4v acc[4][4];
#pragma unroll
    for (int mt = 0; mt < 4; ++mt)
#pragma unroll
      for (int dd = 0; dd < 4; ++dd) acc[mt][dd] = (float4v){0.f, 0.f, 0.f, 0.f};

    int buf = 0;
#pragma unroll
    for (int ks = 0; ks < 4; ++ks) {
      __syncthreads();  // staged W ready; previous buffer free
      if (ks < 3)
        stage6(wfrag_g +
                   (size_t)(((mtile0 + wu) * 4 + (ks + 1)) * 3072 + lane * 8),
               &wlds[buf ^ 1][wu * 3072]);
      const short8v a1h = A1h[ks], a1l = A1l[ks];
      const short8v a2h = A2h[ks], a2l = A2l[ks];
#pragma unroll
      for (int mt = 0; mt < 4; ++mt) {
        const int so = mt * 3072 + lane * 8;
        const short8v w1h = *(const short8v*)&wlds[buf][so + 0 * 512];
        const short8v w1l = *(const short8v*)&wlds[buf][so + 1 * 512];
        const short8v w2h = *(const short8v*)&wlds[buf][so + 2 * 512];
        const short8v w2l = *(const short8v*)&wlds[buf][so + 3 * 512];
        const short8v w3h = *(const short8v*)&wlds[buf][so + 4 * 512];
        const short8v w3l = *(const short8v*)&wlds[buf][so + 5 * 512];
        acc[mt][0] = MFMA(a1h, w1h, acc[mt][0]);
        acc[mt][0] = MFMA(a1h, w1l, acc[mt][0]);
        acc[mt][0] = MFMA(a1l, w1h, acc[mt][0]);
        acc[mt][1] = MFMA(a1h, w2h, acc[mt][1]);
        acc[mt][1] = MFMA(a1h, w2l, acc[mt][1]);
        acc[mt][1] = MFMA(a1l, w2h, acc[mt][1]);
        acc[mt][2] = MFMA(a1h, w3h, acc[mt][2]);
        acc[mt][2] = MFMA(a1h, w3l, acc[mt][2]);
        acc[mt][2] = MFMA(a1l, w3h, acc[mt][2]);
        acc[mt][3] = MFMA(a2h, w1h, acc[mt][3]);
        acc[mt][3] = MFMA(a2h, w1l, acc[mt][3]);
        acc[mt][3] = MFMA(a2l, w1h, acc[mt][3]);
      }
      buf ^= 1;
    }

    // ---- quadrature on accumulators -> wgt bf16 hi/lo (wave-private rows)
#pragma unroll
    for (int mt = 0; mt < 4; ++mt) {
      const int mloc = mt * 16 + (lane & 15);
      const float c1r = mc_lds[mloc][0], c1i = mc_lds[mloc][1];
      const float dd2 = mc_lds[mloc][2], zj2 = mc_lds[mloc][3];
      const float nsp = mc_lds[mloc][4], nso = mc_lds[mloc][5];
      const float al = mc_lds[mloc][6];
#pragma unroll
      for (int r = 0; r < 4; ++r) {
        const int bloc = w * 16 + (lane >> 4) * 4 + r;  // D row = 4g + r
        const float z2v = bsq_lds[bloc][0], dsqv = bsq_lds[bloc][1];
        const float ipr2 = acc[mt][0][r] - c1r;
        const float ipi2 = acc[mt][1][r] - c1i;
        const float zd = acc[mt][2][r];
        const float ad = acc[mt][3][r];
        const float q0 = z2v - 2.f * zd + zj2;
        const float dbase = (dsqv - 2.f * ad + dd2) * nso;
        const float ii2 = ipi2 * ipi2;
        const float e2 = 2.f * ipr2;
        float qacc = 0.f;
#pragma unroll
        for (int kq = 0; kq < 8; ++kq) {
          const float tk = TQ[kq];
          const float wr = fmaf(-tk, dd2, ipr2);
          const float qp = fmaf(wr, wr, ii2);
          const float q2 = fmaf(tk, fmaf(tk, dd2, -e2), q0);
          const float qperp = fmaxf(q2 - qp, 0.f);
          const float arg = fmaf(qp, nsp, fmaf(qperp, nso, dbase));
          qacc = fmaf(WQ[kq], __expf(arg), qacc);
        }
        const float wv = al * qacc;
        const unsigned short h = f32_bf16(wv);
        wgt_hi[bloc][mloc] = h;
        wgt_lo[bloc][mloc] = f32_bf16(wv - bf16_f32(h));
      }
    }

    // ---- That accumulation via MFMA (A = wgt, B = tfrag); wave-private
    // wgt rows -> no barrier needed (same-wave LDS ordering + waitcnt).
    const int mchunk = ms * (MR / 64) + ci;
#pragma unroll
    for (int ks2 = 0; ks2 < 2; ++ks2) {
      const int row = w * 16 + (lane & 15);
      const int colb = ks2 * 32 + (lane >> 4) * 4;
      const ushort4 h0 = *(const ushort4*)&wgt_hi[row][colb];
      const ushort4 h1 = *(const ushort4*)&wgt_hi[row][colb + 16];
      const ushort4 l0 = *(const ushort4*)&wgt_lo[row][colb];
      const ushort4 l1 = *(const ushort4*)&wgt_lo[row][colb + 16];
      const short8v ah = {(short)h0.x, (short)h0.y, (short)h0.z, (short)h0.w,
                          (short)h1.x, (short)h1.y, (short)h1.z, (short)h1.w};
      const short8v alv = {(short)l0.x, (short)l0.y, (short)l0.z, (short)l0.w,
                           (short)l1.x, (short)l1.y, (short)l1.z, (short)l1.w};
#pragma unroll
      for (int ct = 0; ct < 4; ++ct) {
        const size_t toff =
            ((((size_t)mchunk * 4 + ct) * 2 + ks2) * 2) * 512 + lane * 8;
        const short8v th = *(const short8v*)(tfrag_g + toff);
        const short8v tl = *(const short8v*)(tfrag_g + toff + 512);
        Tacc[ct] = MFMA(ah, th, Tacc[ct]);
        Tacc[ct] = MFMA(ah, tl, Tacc[ct]);
        Tacc[ct] = MFMA(alv, th, Tacc[ct]);
      }
    }
  }

  // partial T for this m-split: D layout col = s-local (lane&15),
  // row = 4*(lane>>4) + r.
#pragma unroll
  for (int ct = 0; ct < 4; ++ct)
#pragma unroll
    for (int r = 0; r < 4; ++r)
      part_g[((size_t)ms * B_DIM + (b0 + w * 16 + (lane >> 4) * 4 + r)) *
                 S_DIM +
             ct * 16 + (lane & 15)] = Tacc[ct][r];
}

// ---------------- reduce partials ----------------------------------------
__global__ __launch_bounds__(256) void reduce_parts(float* __restrict__ out) {
  const int i = blockIdx.x * 256 + threadIdx.x;  // [0, 131072)
  float s = 0.f;
#pragma unroll
  for (int p = 0; p < MSPLIT; ++p) s += part_g[(size_t)p * B_DIM * S_DIM + i];
  out[i] = s;
}

extern "C" void kernel_launch(void* const* d_in, const int* in_sizes, int n_in,
                              void* d_out, int out_size, void* d_ws,
                              size_t ws_size, hipStream_t stream) {
  const float* z_re = (const float*)d_in[0];
  const float* z_im = (const float*)d_in[1];
  const float* d_re = (const float*)d_in[2];
  const float* d_im = (const float*)d_in[3];
  const float* zj_re = (const float*)d_in[4];
  const float* zj_im = (const float*)d_in[5];
  const float* dj_re = (const float*)d_in[6];
  const float* dj_im = (const float*)d_in[7];
  const float* That_re = (const float*)d_in[8];
  const float* alpha = (const float*)d_in[10];
  const float* sig_par = (const float*)d_in[11];
  const float* sig_perp = (const float*)d_in[12];

  build_wfrag<<<dim3(1536), dim3(256), 0, stream>>>(zj_re, zj_im, dj_re, dj_im);
  build_tfrag<<<dim3(256), dim3(256), 0, stream>>>(That_re);
  build_mconst<<<dim3(M_DIM / 4), dim3(256), 0, stream>>>(
      dj_re, dj_im, zj_re, zj_im, alpha, sig_par, sig_perp);
  build_bsq<<<dim3(B_DIM / 4), dim3(256), 0, stream>>>(z_re, z_im, d_re, d_im);
  cpsf_mfma<<<dim3((B_DIM / BTILE) * MSPLIT), dim3(256), 0, stream>>>(
      z_re, z_im, d_re, d_im);
  reduce_parts<<<dim3(B_DIM * S_DIM / 256), dim3(256), 0, stream>>>(
      (float*)d_out);
}

// Round 8
// 72.813 us; speedup vs baseline: 9.3473x; 1.4573x over previous
//
#include <hip/hip_runtime.h>
#include <math.h>

#define B_DIM 2048
#define M_DIM 4096
#define N_DIM 64
#define S_DIM 64
#define EPS_TOTAL 0.001f
#define MSPLIT 32
#define MR (M_DIM / MSPLIT)  // 128 m per block
#define BTILE 64             // b per block

typedef __attribute__((ext_vector_type(8))) short short8v;
typedef __attribute__((ext_vector_type(4))) float float4v;

#define MFMA(a, b, c) __builtin_amdgcn_mfma_f32_16x16x32_bf16(a, b, c, 0, 0, 0)

// Module-owned buffers.
// wfrag: [mtile 256][kstep 4][mat 3][split 2][lane 64][8 bf16]  (25.2 MB)
__device__ unsigned short wfrag_g[256 * 4 * 3 * 2 * 64 * 8];
// tfrag: [mchunk 64][ct 4][ks2 2][split 2][lane 64][8 bf16]     (1 MB)
__device__ unsigned short tfrag_g[64 * 4 * 2 * 2 * 64 * 8];
__device__ float mc_g[M_DIM * 8];    // c1r,c1i,dd2,zj2,nsp,nso,alpha,pad
__device__ float bsq_g[B_DIM * 2];   // z2, dsq
__device__ float part_g[(size_t)MSPLIT * B_DIM * S_DIM];  // 16.8 MB

__device__ inline unsigned short f32_bf16(float x) {
  unsigned int u = __float_as_uint(x);
  unsigned int r = (u + 0x7fffu + ((u >> 16) & 1u)) >> 16;  // RNE
  return (unsigned short)r;
}
__device__ inline float bf16_f32(unsigned short h) {
  return __uint_as_float(((unsigned int)h) << 16);
}

// ------------- P1: W + That fragments (bf16 hi/lo, mfma B-layout) --------
__global__ __launch_bounds__(256) void build_frags(
    const float* __restrict__ zj_re, const float* __restrict__ zj_im,
    const float* __restrict__ dj_re, const float* __restrict__ dj_im,
    const float* __restrict__ That_re) {
  const int gid = blockIdx.x * 256 + threadIdx.x;  // [0, 458752)
  if (gid < 393216) {  // ---- wfrag ----
    const int lane = gid & 63;
    const int rest = gid >> 6;  // [mtile][kstep][mat][split]
    const int split = rest & 1;
    int tmp = rest >> 1;
    const int mat = tmp % 3;
    tmp /= 3;
    const int kstep = tmp & 3;
    const int mtile = tmp >> 2;
    const int m = mtile * 16 + (lane & 15);
    const int g = lane >> 4;
    unsigned short o[8];
#pragma unroll
    for (int e = 0; e < 8; ++e) {
      const int k = kstep * 32 + ((e >> 2) << 4) + (g << 2) + (e & 3);
      float v;
      if (k < 64) {  // pairs with z_re / d_re
        v = (mat == 0) ? dj_re[m * 64 + k]
          : (mat == 1) ? -dj_im[m * 64 + k]
                       : zj_re[m * 64 + k];
      } else {       // pairs with z_im / d_im
        const int kk = k - 64;
        v = (mat == 0) ? dj_im[m * 64 + kk]
          : (mat == 1) ? dj_re[m * 64 + kk]
                       : zj_im[m * 64 + kk];
      }
      const unsigned short h = f32_bf16(v);
      o[e] = split ? f32_bf16(v - bf16_f32(h)) : h;
    }
    uint4 u;
    u.x = (unsigned)o[0] | ((unsigned)o[1] << 16);
    u.y = (unsigned)o[2] | ((unsigned)o[3] << 16);
    u.z = (unsigned)o[4] | ((unsigned)o[5] << 16);
    u.w = (unsigned)o[6] | ((unsigned)o[7] << 16);
    *(uint4*)(wfrag_g + (size_t)gid * 8) = u;
  } else {  // ---- tfrag ----
    const int gid2 = gid - 393216;  // [0, 65536)
    const int lane = gid2 & 63;
    const int rest = gid2 >> 6;  // [mchunk][ct][ks2][split]
    const int split = rest & 1;
    const int ks2 = (rest >> 1) & 1;
    const int ct = (rest >> 2) & 3;
    const int mchunk = rest >> 4;
    const int s = ct * 16 + (lane & 15);
    const int g = lane >> 4;
    unsigned short o[8];
#pragma unroll
    for (int e = 0; e < 8; ++e) {
      const int k = ks2 * 32 + ((e >> 2) << 4) + (g << 2) + (e & 3);
      const float v = That_re[(size_t)(mchunk * 64 + k) * S_DIM + s];
      const unsigned short h = f32_bf16(v);
      o[e] = split ? f32_bf16(v - bf16_f32(h)) : h;
    }
    uint4 u;
    u.x = (unsigned)o[0] | ((unsigned)o[1] << 16);
    u.y = (unsigned)o[2] | ((unsigned)o[3] << 16);
    u.z = (unsigned)o[4] | ((unsigned)o[5] << 16);
    u.w = (unsigned)o[6] | ((unsigned)o[7] << 16);
    *(uint4*)(tfrag_g + (size_t)gid2 * 8) = u;
  }
}

// ------------- P2: per-m constants + per-b squared norms -----------------
__global__ __launch_bounds__(256) void build_scalars(
    const float* __restrict__ dj_re, const float* __restrict__ dj_im,
    const float* __restrict__ zj_re, const float* __restrict__ zj_im,
    const float* __restrict__ alpha, const float* __restrict__ sig_par,
    const float* __restrict__ sig_perp,
    const float* __restrict__ z_re, const float* __restrict__ z_im,
    const float* __restrict__ d_re, const float* __restrict__ d_im) {
  const int w = threadIdx.x >> 6, lane = threadIdx.x & 63;
  if (blockIdx.x < M_DIM / 4) {  // ---- mconst ----
    const int m = blockIdx.x * 4 + w;
    const int idx = m * N_DIM + lane;
    const float djr = dj_re[idx], dji = dj_im[idx];
    const float zjr = zj_re[idx], zji = zj_im[idx];
    float dd2 = djr * djr + dji * dji;
    float c1r = djr * zjr + dji * zji;
    float c1i = djr * zji - dji * zjr;
    float zj2 = zjr * zjr + zji * zji;
#pragma unroll
    for (int off = 1; off < 64; off <<= 1) {
      dd2 += __shfl_xor(dd2, off);
      c1r += __shfl_xor(c1r, off);
      c1i += __shfl_xor(c1i, off);
      zj2 += __shfl_xor(zj2, off);
    }
    if (lane == 0) {
      const float sp = sig_par[m], so = sig_perp[m];
      float* o = mc_g + m * 8;
      o[0] = c1r;
      o[1] = c1i;
      o[2] = dd2;
      o[3] = zj2;
      o[4] = -0.5f / fmaf(sp, sp, EPS_TOTAL);
      o[5] = -0.5f / fmaf(so, so, EPS_TOTAL);
      o[6] = alpha[m];
      o[7] = 0.f;
    }
  } else {  // ---- bsq ----
    const int b = (blockIdx.x - M_DIM / 4) * 4 + w;
    const int idx = b * N_DIM + lane;
    const float zr = z_re[idx], zi = z_im[idx];
    const float dr = d_re[idx], di = d_im[idx];
    float z2 = zr * zr + zi * zi;
    float dsq = dr * dr + di * di;
#pragma unroll
    for (int off = 1; off < 64; off <<= 1) {
      z2 += __shfl_xor(z2, off);
      dsq += __shfl_xor(dsq, off);
    }
    if (lane == 0) {
      bsq_g[b * 2] = z2;
      bsq_g[b * 2 + 1] = dsq;
    }
  }
}

// ------------- main: barrier-free MFMA + quadrature + That-MFMA ----------
__global__ __launch_bounds__(256) void cpsf_mfma(
    const float* __restrict__ z_re, const float* __restrict__ z_im,
    const float* __restrict__ d_re, const float* __restrict__ d_im) {
  // Only LDS use: wave-private wgt transpose (no __syncthreads anywhere).
  __shared__ __align__(16) unsigned short wgt_hi[64][68];
  __shared__ __align__(16) unsigned short wgt_lo[64][68];

  const int tid = threadIdx.x;
  const int w = tid >> 6, lane = tid & 63;
  // XCD-aware swizzle over the FULL 1024-block grid (r7 bug: launched 512
  // -> bt only covered [0,16), half of d_out never written).
  // x = xcd, q in [0,128): ms = x + 8*(q&3) in [0,32), bt = q>>2 in [0,32).
  const int q = blockIdx.x >> 3, x = blockIdx.x & 7;
  const int ms = x + 8 * (q & 3);   // [0,32)
  const int bt = q >> 2;            // [0,32)
  const int b0 = bt * BTILE;
  const int g = lane >> 4;

  // ---- A fragments (16 b per wave, K=128, A1=z, A2=d, hi/lo split) ----
  const int bb = b0 + w * 16 + (lane & 15);
  short8v A1h[4], A1l[4], A2h[4], A2l[4];
#pragma unroll
  for (int ks = 0; ks < 4; ++ks) {
#pragma unroll
    for (int e = 0; e < 8; ++e) {
      const int k = ks * 32 + ((e >> 2) << 4) + (g << 2) + (e & 3);
      float a1, a2;
      if (k < 64) {
        a1 = z_re[bb * 64 + k];
        a2 = d_re[bb * 64 + k];
      } else {
        a1 = z_im[bb * 64 + k - 64];
        a2 = d_im[bb * 64 + k - 64];
      }
      const unsigned short h1 = f32_bf16(a1);
      A1h[ks][e] = (short)h1;
      A1l[ks][e] = (short)f32_bf16(a1 - bf16_f32(h1));
      const unsigned short h2 = f32_bf16(a2);
      A2h[ks][e] = (short)h2;
      A2l[ks][e] = (short)f32_bf16(a2 - bf16_f32(h2));
    }
  }

  // per-b squared norms for this thread's 4 output rows (constant over m)
  float bz[4], bd[4];
#pragma unroll
  for (int r = 0; r < 4; ++r) {
    const int bloc = b0 + w * 16 + g * 4 + r;
    bz[r] = bsq_g[bloc * 2];
    bd[r] = bsq_g[bloc * 2 + 1];
  }

  const float TQ[8] = {0.019855071751231885f, 0.101666761293186630f,
                       0.237233795041835510f, 0.408282678752175100f,
                       0.591717321247824900f, 0.762766204958164500f,
                       0.898333238706813370f, 0.980144928248768120f};
  const float WQ[8] = {0.050614268145188130f, 0.111190517226687240f,
                       0.156853322938943640f, 0.181341891689180990f,
                       0.181341891689180990f, 0.156853322938943640f,
                       0.111190517226687240f, 0.050614268145188130f};

  float4v Tacc[4];
#pragma unroll
  for (int i = 0; i < 4; ++i) Tacc[i] = (float4v){0.f, 0.f, 0.f, 0.f};

#pragma unroll
  for (int ci = 0; ci < MR / 64; ++ci) {
    const int m0 = ms * MR + ci * 64;
    const int mtile0 = m0 >> 4;

    // ---- per-mt: K=128 GEMM (direct global W frags) + quadrature ----
#pragma unroll
    for (int mt = 0; mt < 4; ++mt) {
      float4v acc0 = {0.f, 0.f, 0.f, 0.f}, acc1 = acc0, acc2 = acc0,
              acc3 = acc0;
#pragma unroll
      for (int ks = 0; ks < 4; ++ks) {
        const unsigned short* wp =
            wfrag_g + ((size_t)((mtile0 + mt) * 4 + ks) * 6) * 512 + lane * 8;
        const short8v w1h = *(const short8v*)(wp + 0 * 512);
        const short8v w1l = *(const short8v*)(wp + 1 * 512);
        const short8v w2h = *(const short8v*)(wp + 2 * 512);
        const short8v w2l = *(const short8v*)(wp + 3 * 512);
        const short8v w3h = *(const short8v*)(wp + 4 * 512);
        const short8v w3l = *(const short8v*)(wp + 5 * 512);
        const short8v a1h = A1h[ks], a1l = A1l[ks];
        const short8v a2h = A2h[ks], a2l = A2l[ks];
        acc0 = MFMA(a1h, w1h, acc0);
        acc0 = MFMA(a1h, w1l, acc0);
        acc0 = MFMA(a1l, w1h, acc0);
        acc1 = MFMA(a1h, w2h, acc1);
        acc1 = MFMA(a1h, w2l, acc1);
        acc1 = MFMA(a1l, w2h, acc1);
        acc2 = MFMA(a1h, w3h, acc2);
        acc2 = MFMA(a1h, w3l, acc2);
        acc2 = MFMA(a1l, w3h, acc2);
        acc3 = MFMA(a2h, w1h, acc3);
        acc3 = MFMA(a2h, w1l, acc3);
        acc3 = MFMA(a2l, w1h, acc3);
      }

      // quadrature for this mt (per-m constants direct from L1/L2)
      const int mloc = mt * 16 + (lane & 15);
      const float* mcp = mc_g + (size_t)(m0 + mloc) * 8;
      const float c1r = mcp[0], c1i = mcp[1];
      const float dd2 = mcp[2], zj2 = mcp[3];
      const float nsp = mcp[4], nso = mcp[5];
      const float al = mcp[6];
#pragma unroll
      for (int r = 0; r < 4; ++r) {
        const float ipr2 = acc0[r] - c1r;
        const float ipi2 = acc1[r] - c1i;
        const float q0 = bz[r] - 2.f * acc2[r] + zj2;
        const float dbase = (bd[r] - 2.f * acc3[r] + dd2) * nso;
        const float ii2 = ipi2 * ipi2;
        const float e2 = 2.f * ipr2;
        float qacc = 0.f;
#pragma unroll
        for (int kq = 0; kq < 8; ++kq) {
          const float tk = TQ[kq];
          const float wr = fmaf(-tk, dd2, ipr2);
          const float qp = fmaf(wr, wr, ii2);
          const float q2 = fmaf(tk, fmaf(tk, dd2, -e2), q0);
          const float qperp = fmaxf(q2 - qp, 0.f);
          const float arg = fmaf(qp, nsp, fmaf(qperp, nso, dbase));
          qacc = fmaf(WQ[kq], __expf(arg), qacc);
        }
        const float wv = al * qacc;
        const unsigned short h = f32_bf16(wv);
        const int bloc = w * 16 + g * 4 + r;
        wgt_hi[bloc][mloc] = h;
        wgt_lo[bloc][mloc] = f32_bf16(wv - bf16_f32(h));
      }
    }

    // ---- That accumulation via MFMA (wave-private wgt rows; in-wave
    // LDS ordering via waitcnt, no barrier) ----
    const int mchunk = ms * (MR / 64) + ci;
#pragma unroll
    for (int ks2 = 0; ks2 < 2; ++ks2) {
      const int row = w * 16 + (lane & 15);
      const int colb = ks2 * 32 + g * 4;
      const ushort4 h0 = *(const ushort4*)&wgt_hi[row][colb];
      const ushort4 h1 = *(const ushort4*)&wgt_hi[row][colb + 16];
      const ushort4 l0 = *(const ushort4*)&wgt_lo[row][colb];
      const ushort4 l1 = *(const ushort4*)&wgt_lo[row][colb + 16];
      const short8v ah = {(short)h0.x, (short)h0.y, (short)h0.z, (short)h0.w,
                          (short)h1.x, (short)h1.y, (short)h1.z, (short)h1.w};
      const short8v alv = {(short)l0.x, (short)l0.y, (short)l0.z, (short)l0.w,
                           (short)l1.x, (short)l1.y, (short)l1.z, (short)l1.w};
#pragma unroll
      for (int ct = 0; ct < 4; ++ct) {
        const size_t toff =
            ((((size_t)mchunk * 4 + ct) * 2 + ks2) * 2) * 512 + lane * 8;
        const short8v th = *(const short8v*)(tfrag_g + toff);
        const short8v tl = *(const short8v*)(tfrag_g + toff + 512);
        Tacc[ct] = MFMA(ah, th, Tacc[ct]);
        Tacc[ct] = MFMA(ah, tl, Tacc[ct]);
        Tacc[ct] = MFMA(alv, th, Tacc[ct]);
      }
    }
  }

  // partial T for this m-split: D row = 4g + r, col = ct*16+(lane&15).
#pragma unroll
  for (int ct = 0; ct < 4; ++ct)
#pragma unroll
    for (int r = 0; r < 4; ++r)
      part_g[((size_t)ms * B_DIM + (b0 + w * 16 + g * 4 + r)) * S_DIM +
             ct * 16 + (lane & 15)] = Tacc[ct][r];
}

// ------------- reduce partials -------------------------------------------
__global__ __launch_bounds__(256) void reduce_parts(float* __restrict__ out) {
  const int i = blockIdx.x * 256 + threadIdx.x;  // [0, 131072)
  float s = 0.f;
#pragma unroll
  for (int p = 0; p < MSPLIT; ++p) s += part_g[(size_t)p * B_DIM * S_DIM + i];
  out[i] = s;
}

extern "C" void kernel_launch(void* const* d_in, const int* in_sizes, int n_in,
                              void* d_out, int out_size, void* d_ws,
                              size_t ws_size, hipStream_t stream) {
  const float* z_re = (const float*)d_in[0];
  const float* z_im = (const float*)d_in[1];
  const float* d_re = (const float*)d_in[2];
  const float* d_im = (const float*)d_in[3];
  const float* zj_re = (const float*)d_in[4];
  const float* zj_im = (const float*)d_in[5];
  const float* dj_re = (const float*)d_in[6];
  const float* dj_im = (const float*)d_in[7];
  const float* That_re = (const float*)d_in[8];
  const float* alpha = (const float*)d_in[10];
  const float* sig_par = (const float*)d_in[11];
  const float* sig_perp = (const float*)d_in[12];

  build_frags<<<dim3(1792), dim3(256), 0, stream>>>(zj_re, zj_im, dj_re,
                                                    dj_im, That_re);
  build_scalars<<<dim3(M_DIM / 4 + B_DIM / 4), dim3(256), 0, stream>>>(
      dj_re, dj_im, zj_re, zj_im, alpha, sig_par, sig_perp, z_re, z_im, d_re,
      d_im);
  // FULL grid: 32 b-tiles x 32 m-splits = 1024 blocks (r7 launched 512).
  cpsf_mfma<<<dim3((B_DIM / BTILE) * MSPLIT), dim3(256), 0, stream>>>(
      z_re, z_im, d_re, d_im);
  reduce_parts<<<dim3(B_DIM * S_DIM / 256), dim3(256), 0, stream>>>(
      (float*)d_out);
}

// Round 9
// 66.244 us; speedup vs baseline: 10.2742x; 1.0992x over previous
//
#include <hip/hip_runtime.h>
#include <math.h>

#define B_DIM 2048
#define M_DIM 4096
#define N_DIM 64
#define S_DIM 64
#define EPS_TOTAL 0.001f
#define MSPLIT 32
#define MR (M_DIM / MSPLIT)  // 128 m per block
#define BTILE 64             // b per block

typedef __attribute__((ext_vector_type(8))) short short8v;
typedef __attribute__((ext_vector_type(4))) short short4v;
typedef __attribute__((ext_vector_type(4))) float float4v;

#define MFMA(a, b, c) __builtin_amdgcn_mfma_f32_16x16x32_bf16(a, b, c, 0, 0, 0)

// Module-owned buffers.
// wfrag: [mtile 256][kstep 4][mat 3][split 2][lane 64][8 bf16]  (25.2 MB)
__device__ unsigned short wfrag_g[256 * 4 * 3 * 2 * 64 * 8];
// tfrag: [mchunk 64][ct 4][ks2 2][split 2][lane 64][8 bf16]     (1 MB)
__device__ unsigned short tfrag_g[64 * 4 * 2 * 2 * 64 * 8];
// mc: [m][8] = c1r, c1i, zj2, Km, A2, B2, nsoL, nspmoL  (quad-poly consts)
__device__ __align__(16) float mc_g[M_DIM * 8];
__device__ float bsq_g[B_DIM * 2];   // z2, dsq
__device__ float part_g[(size_t)MSPLIT * B_DIM * S_DIM];  // 16.8 MB

__device__ inline unsigned short f32_bf16(float x) {
  unsigned int u = __float_as_uint(x);
  unsigned int r = (u + 0x7fffu + ((u >> 16) & 1u)) >> 16;  // RNE
  return (unsigned short)r;
}
__device__ inline float bf16_f32(unsigned short h) {
  return __uint_as_float(((unsigned int)h) << 16);
}
__device__ inline float fast_exp2(float x) {
#if __has_builtin(__builtin_amdgcn_exp2f)
  return __builtin_amdgcn_exp2f(x);
#else
  float r;
  asm("v_exp_f32 %0, %1" : "=v"(r) : "v"(x));
  return r;
#endif
}

// ------------- P1: W + That fragments (bf16 hi/lo, mfma B-layout) --------
__global__ __launch_bounds__(256) void build_frags(
    const float* __restrict__ zj_re, const float* __restrict__ zj_im,
    const float* __restrict__ dj_re, const float* __restrict__ dj_im,
    const float* __restrict__ That_re) {
  const int gid = blockIdx.x * 256 + threadIdx.x;  // [0, 458752)
  if (gid < 393216) {  // ---- wfrag ----
    const int lane = gid & 63;
    const int rest = gid >> 6;  // [mtile][kstep][mat][split]
    const int split = rest & 1;
    int tmp = rest >> 1;
    const int mat = tmp % 3;
    tmp /= 3;
    const int kstep = tmp & 3;
    const int mtile = tmp >> 2;
    const int m = mtile * 16 + (lane & 15);
    const int g = lane >> 4;
    unsigned short o[8];
#pragma unroll
    for (int e = 0; e < 8; ++e) {
      const int k = kstep * 32 + ((e >> 2) << 4) + (g << 2) + (e & 3);
      float v;
      if (k < 64) {  // pairs with z_re / d_re
        v = (mat == 0) ? dj_re[m * 64 + k]
          : (mat == 1) ? -dj_im[m * 64 + k]
                       : zj_re[m * 64 + k];
      } else {       // pairs with z_im / d_im
        const int kk = k - 64;
        v = (mat == 0) ? dj_im[m * 64 + kk]
          : (mat == 1) ? dj_re[m * 64 + kk]
                       : zj_im[m * 64 + kk];
      }
      const unsigned short h = f32_bf16(v);
      o[e] = split ? f32_bf16(v - bf16_f32(h)) : h;
    }
    uint4 u;
    u.x = (unsigned)o[0] | ((unsigned)o[1] << 16);
    u.y = (unsigned)o[2] | ((unsigned)o[3] << 16);
    u.z = (unsigned)o[4] | ((unsigned)o[5] << 16);
    u.w = (unsigned)o[6] | ((unsigned)o[7] << 16);
    *(uint4*)(wfrag_g + (size_t)gid * 8) = u;
  } else {  // ---- tfrag ----
    const int gid2 = gid - 393216;  // [0, 65536)
    const int lane = gid2 & 63;
    const int rest = gid2 >> 6;  // [mchunk][ct][ks2][split]
    const int split = rest & 1;
    const int ks2 = (rest >> 1) & 1;
    const int ct = (rest >> 2) & 3;
    const int mchunk = rest >> 4;
    const int s = ct * 16 + (lane & 15);
    const int g = lane >> 4;
    unsigned short o[8];
#pragma unroll
    for (int e = 0; e < 8; ++e) {
      const int k = ks2 * 32 + ((e >> 2) << 4) + (g << 2) + (e & 3);
      const float v = That_re[(size_t)(mchunk * 64 + k) * S_DIM + s];
      const unsigned short h = f32_bf16(v);
      o[e] = split ? f32_bf16(v - bf16_f32(h)) : h;
    }
    uint4 u;
    u.x = (unsigned)o[0] | ((unsigned)o[1] << 16);
    u.y = (unsigned)o[2] | ((unsigned)o[3] << 16);
    u.z = (unsigned)o[4] | ((unsigned)o[5] << 16);
    u.w = (unsigned)o[6] | ((unsigned)o[7] << 16);
    *(uint4*)(tfrag_g + (size_t)gid2 * 8) = u;
  }
}

// ------------- P2: per-m poly constants + per-b squared norms ------------
// arg(t) = A2*t^2 + B2*t + C, all pre-scaled by log2(e); exp via exp2.
// C = nspmoL*(ipr2^2+ipi2^2) + nsoL*q0 + (bd-2ad)*nsoL + Km,
// Km = dd2*nsoL + log2(alpha)  (alpha folded into the exponent).
__global__ __launch_bounds__(256) void build_scalars(
    const float* __restrict__ dj_re, const float* __restrict__ dj_im,
    const float* __restrict__ zj_re, const float* __restrict__ zj_im,
    const float* __restrict__ alpha, const float* __restrict__ sig_par,
    const float* __restrict__ sig_perp,
    const float* __restrict__ z_re, const float* __restrict__ z_im,
    const float* __restrict__ d_re, const float* __restrict__ d_im) {
  const int w = threadIdx.x >> 6, lane = threadIdx.x & 63;
  if (blockIdx.x < M_DIM / 4) {  // ---- mconst ----
    const int m = blockIdx.x * 4 + w;
    const int idx = m * N_DIM + lane;
    const float djr = dj_re[idx], dji = dj_im[idx];
    const float zjr = zj_re[idx], zji = zj_im[idx];
    float dd2 = djr * djr + dji * dji;
    float c1r = djr * zjr + dji * zji;
    float c1i = djr * zji - dji * zjr;
    float zj2 = zjr * zjr + zji * zji;
#pragma unroll
    for (int off = 1; off < 64; off <<= 1) {
      dd2 += __shfl_xor(dd2, off);
      c1r += __shfl_xor(c1r, off);
      c1i += __shfl_xor(c1i, off);
      zj2 += __shfl_xor(zj2, off);
    }
    if (lane == 0) {
      const float L = 1.4426950408889634f;
      const float sp = sig_par[m], so = sig_perp[m];
      const float nsp = -0.5f / fmaf(sp, sp, EPS_TOTAL);
      const float nso = -0.5f / fmaf(so, so, EPS_TOTAL);
      const float nsoL = nso * L;
      const float nspmoL = (nsp - nso) * L;
      const float t = nspmoL * dd2 + nsoL;
      float* o = mc_g + m * 8;
      o[0] = c1r;
      o[1] = c1i;
      o[2] = zj2;
      o[3] = dd2 * nsoL + log2f(alpha[m]);  // Km
      o[4] = dd2 * t;                        // A2
      o[5] = -2.f * t;                       // B2
      o[6] = nsoL;
      o[7] = nspmoL;
    }
  } else {  // ---- bsq ----
    const int b = (blockIdx.x - M_DIM / 4) * 4 + w;
    const int idx = b * N_DIM + lane;
    const float zr = z_re[idx], zi = z_im[idx];
    const float dr = d_re[idx], di = d_im[idx];
    float z2 = zr * zr + zi * zi;
    float dsq = dr * dr + di * di;
#pragma unroll
    for (int off = 1; off < 64; off <<= 1) {
      z2 += __shfl_xor(z2, off);
      dsq += __shfl_xor(dsq, off);
    }
    if (lane == 0) {
      bsq_g[b * 2] = z2;
      bsq_g[b * 2 + 1] = dsq;
    }
  }
}

// ------------- main: barrier-free MFMA + poly quadrature + That-MFMA -----
__global__ __launch_bounds__(256) void cpsf_mfma(
    const float* __restrict__ z_re, const float* __restrict__ z_im,
    const float* __restrict__ d_re, const float* __restrict__ d_im) {
  // Only LDS use: wave-private wgt transpose (no __syncthreads anywhere).
  __shared__ __align__(16) unsigned short wgt_hi[64][68];

  const int tid = threadIdx.x;
  const int w = tid >> 6, lane = tid & 63;
  // XCD-aware swizzle over the full 1024-block grid.
  const int q = blockIdx.x >> 3, x = blockIdx.x & 7;
  const int ms = x + 8 * (q & 3);   // [0,32)
  const int bt = q >> 2;            // [0,32)
  const int b0 = bt * BTILE;
  const int g = lane >> 4;

  // ---- A fragments (16 b per wave, K=128, A1=z, A2=d, hi/lo split) ----
  // k<64 vs >=64 is uniform per (ks,half): float4 loads, no branches.
  const int bb = b0 + w * 16 + (lane & 15);
  short8v A1h[4], A1l[4], A2h[4], A2l[4];
#pragma unroll
  for (int ks = 0; ks < 4; ++ks) {
#pragma unroll
    for (int h = 0; h < 2; ++h) {
      const int C = ks * 32 + h * 16;
      const float* p1 = (C < 64) ? (z_re + bb * 64 + C) : (z_im + bb * 64 + C - 64);
      const float* p2 = (C < 64) ? (d_re + bb * 64 + C) : (d_im + bb * 64 + C - 64);
      const float4 vz = *(const float4*)(p1 + g * 4);
      const float4 vd = *(const float4*)(p2 + g * 4);
      const float az[4] = {vz.x, vz.y, vz.z, vz.w};
      const float ad[4] = {vd.x, vd.y, vd.z, vd.w};
#pragma unroll
      for (int e2 = 0; e2 < 4; ++e2) {
        const int e = h * 4 + e2;
        const unsigned short h1 = f32_bf16(az[e2]);
        A1h[ks][e] = (short)h1;
        A1l[ks][e] = (short)f32_bf16(az[e2] - bf16_f32(h1));
        const unsigned short h2 = f32_bf16(ad[e2]);
        A2h[ks][e] = (short)h2;
        A2l[ks][e] = (short)f32_bf16(ad[e2] - bf16_f32(h2));
      }
    }
  }

  // per-b squared norms for this thread's 4 output rows (constant over m)
  float bz[4], bd[4];
#pragma unroll
  for (int r = 0; r < 4; ++r) {
    const int bloc = b0 + w * 16 + g * 4 + r;
    bz[r] = bsq_g[bloc * 2];
    bd[r] = bsq_g[bloc * 2 + 1];
  }

  const float TQ[8] = {0.019855071751231885f, 0.101666761293186630f,
                       0.237233795041835510f, 0.408282678752175100f,
                       0.591717321247824900f, 0.762766204958164500f,
                       0.898333238706813370f, 0.980144928248768120f};
  const float WQ[8] = {0.050614268145188130f, 0.111190517226687240f,
                       0.156853322938943640f, 0.181341891689180990f,
                       0.181341891689180990f, 0.156853322938943640f,
                       0.111190517226687240f, 0.050614268145188130f};

  float4v Tacc[4];
#pragma unroll
  for (int i = 0; i < 4; ++i) Tacc[i] = (float4v){0.f, 0.f, 0.f, 0.f};

#pragma unroll
  for (int ci = 0; ci < MR / 64; ++ci) {
    const int m0 = ms * MR + ci * 64;
    const int mtile0 = m0 >> 4;

    // ---- per-mt: K=128 GEMM (direct global W frags) + poly quadrature ----
#pragma unroll
    for (int mt = 0; mt < 4; ++mt) {
      float4v acc0 = {0.f, 0.f, 0.f, 0.f}, acc1 = acc0, acc2 = acc0,
              acc3 = acc0;
#pragma unroll
      for (int ks = 0; ks < 4; ++ks) {
        const unsigned short* wp =
            wfrag_g + ((size_t)((mtile0 + mt) * 4 + ks) * 6) * 512 + lane * 8;
        const short8v w1h = *(const short8v*)(wp + 0 * 512);
        const short8v w1l = *(const short8v*)(wp + 1 * 512);
        const short8v w2h = *(const short8v*)(wp + 2 * 512);
        const short8v w2l = *(const short8v*)(wp + 3 * 512);
        const short8v w3h = *(const short8v*)(wp + 4 * 512);
        const short8v w3l = *(const short8v*)(wp + 5 * 512);
        const short8v a1h = A1h[ks], a1l = A1l[ks];
        const short8v a2h = A2h[ks], a2l = A2l[ks];
        acc0 = MFMA(a1h, w1h, acc0);
        acc0 = MFMA(a1h, w1l, acc0);
        acc0 = MFMA(a1l, w1h, acc0);
        acc1 = MFMA(a1h, w2h, acc1);
        acc1 = MFMA(a1h, w2l, acc1);
        acc1 = MFMA(a1l, w2h, acc1);
        acc2 = MFMA(a1h, w3h, acc2);
        acc2 = MFMA(a1h, w3l, acc2);
        acc2 = MFMA(a1l, w3h, acc2);
        acc3 = MFMA(a2h, w1h, acc3);
        acc3 = MFMA(a2h, w1l, acc3);
        acc3 = MFMA(a2l, w1h, acc3);
      }

      // poly quadrature: arg(t) = A2 t^2 + B2 t + C, exp2, alpha folded.
      const int mloc = mt * 16 + (lane & 15);
      const float4 mA = *(const float4*)(mc_g + (size_t)(m0 + mloc) * 8);
      const float4 mB = *(const float4*)(mc_g + (size_t)(m0 + mloc) * 8 + 4);
      const float c1r = mA.x, c1i = mA.y, zj2 = mA.z, Km = mA.w;
      const float A2 = mB.x, B2 = mB.y, nsoL = mB.z, nspmoL = mB.w;
#pragma unroll
      for (int r = 0; r < 4; ++r) {
        const float ipr2 = acc0[r] - c1r;
        const float ipi2 = acc1[r] - c1i;
        const float q0 = fmaf(-2.f, acc2[r], bz[r]) + zj2;
        const float db = fmaf(fmaf(-2.f, acc3[r], bd[r]), nsoL, Km);
        const float r2 = fmaf(ipr2, ipr2, ipi2 * ipi2);
        const float bq = ipr2 * B2;
        const float cc = fmaf(nspmoL, r2, fmaf(nsoL, q0, db));
        float qacc = 0.f;
#pragma unroll
        for (int kq = 0; kq < 8; ++kq) {
          const float tk = TQ[kq];
          const float arg = fmaf(fmaf(A2, tk, bq), tk, cc);
          qacc = fmaf(WQ[kq], fast_exp2(arg), qacc);
        }
        const int bloc = w * 16 + g * 4 + r;
        wgt_hi[bloc][mloc] = f32_bf16(qacc);
      }
    }

    // ---- That accumulation via MFMA (wgt single-bf16 x tfrag hi/lo);
    // wave-private wgt rows -> in-wave LDS ordering, no barrier ----
    const int mchunk = ms * (MR / 64) + ci;
#pragma unroll
    for (int ks2 = 0; ks2 < 2; ++ks2) {
      const int row = w * 16 + (lane & 15);
      const int colb = ks2 * 32 + g * 4;
      const short4v p0 = *(const short4v*)&wgt_hi[row][colb];
      const short4v p1 = *(const short4v*)&wgt_hi[row][colb + 16];
      const short8v ah = __builtin_shufflevector(p0, p1, 0, 1, 2, 3, 4, 5, 6, 7);
#pragma unroll
      for (int ct = 0; ct < 4; ++ct) {
        const size_t toff =
            ((((size_t)mchunk * 4 + ct) * 2 + ks2) * 2) * 512 + lane * 8;
        const short8v th = *(const short8v*)(tfrag_g + toff);
        const short8v tl = *(const short8v*)(tfrag_g + toff + 512);
        Tacc[ct] = MFMA(ah, th, Tacc[ct]);
        Tacc[ct] = MFMA(ah, tl, Tacc[ct]);
      }
    }
  }

  // partial T for this m-split: D row = 4g + r, col = ct*16+(lane&15).
#pragma unroll
  for (int ct = 0; ct < 4; ++ct)
#pragma unroll
    for (int r = 0; r < 4; ++r)
      part_g[((size_t)ms * B_DIM + (b0 + w * 16 + g * 4 + r)) * S_DIM +
             ct * 16 + (lane & 15)] = Tacc[ct][r];
}

// ------------- reduce partials -------------------------------------------
__global__ __launch_bounds__(256) void reduce_parts(float* __restrict__ out) {
  const int i = blockIdx.x * 256 + threadIdx.x;  // [0, 131072)
  float s = 0.f;
#pragma unroll
  for (int p = 0; p < MSPLIT; ++p) s += part_g[(size_t)p * B_DIM * S_DIM + i];
  out[i] = s;
}

extern "C" void kernel_launch(void* const* d_in, const int* in_sizes, int n_in,
                              void* d_out, int out_size, void* d_ws,
                              size_t ws_size, hipStream_t stream) {
  const float* z_re = (const float*)d_in[0];
  const float* z_im = (const float*)d_in[1];
  const float* d_re = (const float*)d_in[2];
  const float* d_im = (const float*)d_in[3];
  const float* zj_re = (const float*)d_in[4];
  const float* zj_im = (const float*)d_in[5];
  const float* dj_re = (const float*)d_in[6];
  const float* dj_im = (const float*)d_in[7];
  const float* That_re = (const float*)d_in[8];
  const float* alpha = (const float*)d_in[10];
  const float* sig_par = (const float*)d_in[11];
  const float* sig_perp = (const float*)d_in[12];

  build_frags<<<dim3(1792), dim3(256), 0, stream>>>(zj_re, zj_im, dj_re,
                                                    dj_im, That_re);
  build_scalars<<<dim3(M_DIM / 4 + B_DIM / 4), dim3(256), 0, stream>>>(
      dj_re, dj_im, zj_re, zj_im, alpha, sig_par, sig_perp, z_re, z_im, d_re,
      d_im);
  cpsf_mfma<<<dim3((B_DIM / BTILE) * MSPLIT), dim3(256), 0, stream>>>(
      z_re, z_im, d_re, d_im);
  reduce_parts<<<dim3(B_DIM * S_DIM / 256), dim3(256), 0, stream>>>(
      (float*)d_out);
}

// Round 10
// 53.946 us; speedup vs baseline: 12.6164x; 1.2280x over previous
//
#include <hip/hip_runtime.h>
#include <math.h>

#define B_DIM 2048
#define M_DIM 4096
#define N_DIM 64
#define S_DIM 64
#define EPS_TOTAL 0.001f
#define MSPLIT 32
#define MR (M_DIM / MSPLIT)  // 128 m per block
#define BTILE 64             // b per block

typedef __attribute__((ext_vector_type(8))) short short8v;
typedef __attribute__((ext_vector_type(4))) short short4v;
typedef __attribute__((ext_vector_type(4))) float float4v;

#define MFMA(a, b, c) __builtin_amdgcn_mfma_f32_16x16x32_bf16(a, b, c, 0, 0, 0)

// Module-owned buffers.
// wfrag: [mtile 256][kstep 4][mat 2 (W1=dj, W3=zj)][split 2][lane 64][8]
//        = 4.2 MB. W2 = [-dj_im; dj_re] is DERIVED (k-slice swap of W1 with
//        the sign handled by a split accumulator) -> not stored.
__device__ unsigned short wfrag_g[256 * 4 * 2 * 2 * 64 * 8];
// tfrag: [mchunk 64][ct 4][ks2 2][split 2][lane 64][8 bf16]  (1 MB)
__device__ unsigned short tfrag_g[64 * 4 * 2 * 2 * 64 * 8];
// mc: [m][8] = c1r, c1i, zj2, Km, A2, B2, nsoL, nspmoL  (quad-poly consts)
__device__ __align__(16) float mc_g[M_DIM * 8];
__device__ float bsq_g[B_DIM * 2];   // z2, dsq
__device__ float part_g[(size_t)MSPLIT * B_DIM * S_DIM];  // 16.8 MB

__device__ inline unsigned short f32_bf16(float x) {
  unsigned int u = __float_as_uint(x);
  unsigned int r = (u + 0x7fffu + ((u >> 16) & 1u)) >> 16;  // RNE
  return (unsigned short)r;
}
__device__ inline float bf16_f32(unsigned short h) {
  return __uint_as_float(((unsigned int)h) << 16);
}
__device__ inline float fast_exp2(float x) {
#if __has_builtin(__builtin_amdgcn_exp2f)
  return __builtin_amdgcn_exp2f(x);
#else
  float r;
  asm("v_exp_f32 %0, %1" : "=v"(r) : "v"(x));
  return r;
#endif
}

// ------------- P1 (merged): fragments + per-m consts + per-b norms -------
// blocks [0,1280): wfrag (gid<262144) / tfrag; [1280,2304): mconst;
// [2304,2816): bsq.
__global__ __launch_bounds__(256) void build_all(
    const float* __restrict__ zj_re, const float* __restrict__ zj_im,
    const float* __restrict__ dj_re, const float* __restrict__ dj_im,
    const float* __restrict__ That_re,
    const float* __restrict__ alpha, const float* __restrict__ sig_par,
    const float* __restrict__ sig_perp,
    const float* __restrict__ z_re, const float* __restrict__ z_im,
    const float* __restrict__ d_re, const float* __restrict__ d_im) {
  if (blockIdx.x < 1280) {
    const int gid = blockIdx.x * 256 + threadIdx.x;  // [0, 327680)
    if (gid < 262144) {  // ---- wfrag: [mtile][ks][mat][split] ----
      const int lane = gid & 63;
      const int rest = gid >> 6;
      const int split = rest & 1;
      const int mat = (rest >> 1) & 1;   // 0 = W1 (dj), 1 = W3 (zj)
      const int ks = (rest >> 2) & 3;
      const int mtile = rest >> 4;
      const int m = mtile * 16 + (lane & 15);
      const int g = lane >> 4;
      unsigned short o[8];
#pragma unroll
      for (int e = 0; e < 8; ++e) {
        const int k = ks * 32 + ((e >> 2) << 4) + (g << 2) + (e & 3);
        float v;
        if (k < 64) {
          v = mat ? zj_re[m * 64 + k] : dj_re[m * 64 + k];
        } else {
          const int kk = k - 64;
          v = mat ? zj_im[m * 64 + kk] : dj_im[m * 64 + kk];
        }
        const unsigned short h = f32_bf16(v);
        o[e] = split ? f32_bf16(v - bf16_f32(h)) : h;
      }
      uint4 u;
      u.x = (unsigned)o[0] | ((unsigned)o[1] << 16);
      u.y = (unsigned)o[2] | ((unsigned)o[3] << 16);
      u.z = (unsigned)o[4] | ((unsigned)o[5] << 16);
      u.w = (unsigned)o[6] | ((unsigned)o[7] << 16);
      *(uint4*)(wfrag_g + (size_t)gid * 8) = u;
    } else {  // ---- tfrag ----
      const int gid2 = gid - 262144;  // [0, 65536)
      const int lane = gid2 & 63;
      const int rest = gid2 >> 6;  // [mchunk][ct][ks2][split]
      const int split = rest & 1;
      const int ks2 = (rest >> 1) & 1;
      const int ct = (rest >> 2) & 3;
      const int mchunk = rest >> 4;
      const int s = ct * 16 + (lane & 15);
      const int g = lane >> 4;
      unsigned short o[8];
#pragma unroll
      for (int e = 0; e < 8; ++e) {
        const int k = ks2 * 32 + ((e >> 2) << 4) + (g << 2) + (e & 3);
        const float v = That_re[(size_t)(mchunk * 64 + k) * S_DIM + s];
        const unsigned short h = f32_bf16(v);
        o[e] = split ? f32_bf16(v - bf16_f32(h)) : h;
      }
      uint4 u;
      u.x = (unsigned)o[0] | ((unsigned)o[1] << 16);
      u.y = (unsigned)o[2] | ((unsigned)o[3] << 16);
      u.z = (unsigned)o[4] | ((unsigned)o[5] << 16);
      u.w = (unsigned)o[6] | ((unsigned)o[7] << 16);
      *(uint4*)(tfrag_g + (size_t)gid2 * 8) = u;
    }
  } else if (blockIdx.x < 1280 + M_DIM / 4) {  // ---- mconst ----
    const int w = threadIdx.x >> 6, lane = threadIdx.x & 63;
    const int m = (blockIdx.x - 1280) * 4 + w;
    const int idx = m * N_DIM + lane;
    const float djr = dj_re[idx], dji = dj_im[idx];
    const float zjr = zj_re[idx], zji = zj_im[idx];
    float dd2 = djr * djr + dji * dji;
    float c1r = djr * zjr + dji * zji;
    float c1i = djr * zji - dji * zjr;
    float zj2 = zjr * zjr + zji * zji;
#pragma unroll
    for (int off = 1; off < 64; off <<= 1) {
      dd2 += __shfl_xor(dd2, off);
      c1r += __shfl_xor(c1r, off);
      c1i += __shfl_xor(c1i, off);
      zj2 += __shfl_xor(zj2, off);
    }
    if (lane == 0) {
      const float L = 1.4426950408889634f;
      const float sp = sig_par[m], so = sig_perp[m];
      const float nsp = -0.5f / fmaf(sp, sp, EPS_TOTAL);
      const float nso = -0.5f / fmaf(so, so, EPS_TOTAL);
      const float nsoL = nso * L;
      const float nspmoL = (nsp - nso) * L;
      const float t = nspmoL * dd2 + nsoL;
      float* o = mc_g + m * 8;
      o[0] = c1r;
      o[1] = c1i;
      o[2] = zj2;
      o[3] = dd2 * nsoL + log2f(alpha[m]);  // Km
      o[4] = dd2 * t;                        // A2
      o[5] = -2.f * t;                       // B2
      o[6] = nsoL;
      o[7] = nspmoL;
    }
  } else {  // ---- bsq ----
    const int w = threadIdx.x >> 6, lane = threadIdx.x & 63;
    const int b = (blockIdx.x - 1280 - M_DIM / 4) * 4 + w;
    const int idx = b * N_DIM + lane;
    const float zr = z_re[idx], zi = z_im[idx];
    const float dr = d_re[idx], di = d_im[idx];
    float z2 = zr * zr + zi * zi;
    float dsq = dr * dr + di * di;
#pragma unroll
    for (int off = 1; off < 64; off <<= 1) {
      z2 += __shfl_xor(z2, off);
      dsq += __shfl_xor(dsq, off);
    }
    if (lane == 0) {
      bsq_g[b * 2] = z2;
      bsq_g[b * 2 + 1] = dsq;
    }
  }
}

// ------------- main: barrier-free MFMA + poly quadrature + That-MFMA -----
__global__ __launch_bounds__(256) void cpsf_mfma(
    const float* __restrict__ z_re, const float* __restrict__ z_im,
    const float* __restrict__ d_re, const float* __restrict__ d_im) {
  // Only LDS use: wave-private wgt transpose (no __syncthreads anywhere).
  __shared__ __align__(16) unsigned short wgt_hi[64][68];

  const int tid = threadIdx.x;
  const int w = tid >> 6, lane = tid & 63;
  // XCD-aware swizzle over the full 1024-block grid.
  const int q = blockIdx.x >> 3, x = blockIdx.x & 7;
  const int ms = x + 8 * (q & 3);   // [0,32)
  const int bt = q >> 2;            // [0,32)
  const int b0 = bt * BTILE;
  const int g = lane >> 4;

  // ---- A fragments (16 b per wave, K=128, A1=z, A2=d, hi/lo split) ----
  const int bb = b0 + w * 16 + (lane & 15);
  short8v A1h[4], A1l[4], A2h[4], A2l[4];
#pragma unroll
  for (int ks = 0; ks < 4; ++ks) {
#pragma unroll
    for (int h = 0; h < 2; ++h) {
      const int C = ks * 32 + h * 16;
      const float* p1 = (C < 64) ? (z_re + bb * 64 + C) : (z_im + bb * 64 + C - 64);
      const float* p2 = (C < 64) ? (d_re + bb * 64 + C) : (d_im + bb * 64 + C - 64);
      const float4 vz = *(const float4*)(p1 + g * 4);
      const float4 vd = *(const float4*)(p2 + g * 4);
      const float az[4] = {vz.x, vz.y, vz.z, vz.w};
      const float ad[4] = {vd.x, vd.y, vd.z, vd.w};
#pragma unroll
      for (int e2 = 0; e2 < 4; ++e2) {
        const int e = h * 4 + e2;
        const unsigned short h1 = f32_bf16(az[e2]);
        A1h[ks][e] = (short)h1;
        A1l[ks][e] = (short)f32_bf16(az[e2] - bf16_f32(h1));
        const unsigned short h2 = f32_bf16(ad[e2]);
        A2h[ks][e] = (short)h2;
        A2l[ks][e] = (short)f32_bf16(ad[e2] - bf16_f32(h2));
      }
    }
  }

  // per-b squared norms for this thread's 4 output rows (constant over m)
  float bz[4], bd[4];
#pragma unroll
  for (int r = 0; r < 4; ++r) {
    const int bloc = b0 + w * 16 + g * 4 + r;
    bz[r] = bsq_g[bloc * 2];
    bd[r] = bsq_g[bloc * 2 + 1];
  }

  const float TQ[8] = {0.019855071751231885f, 0.101666761293186630f,
                       0.237233795041835510f, 0.408282678752175100f,
                       0.591717321247824900f, 0.762766204958164500f,
                       0.898333238706813370f, 0.980144928248768120f};
  const float WQ[8] = {0.050614268145188130f, 0.111190517226687240f,
                       0.156853322938943640f, 0.181341891689180990f,
                       0.181341891689180990f, 0.156853322938943640f,
                       0.111190517226687240f, 0.050614268145188130f};

  float4v Tacc[4];
#pragma unroll
  for (int i = 0; i < 4; ++i) Tacc[i] = (float4v){0.f, 0.f, 0.f, 0.f};

#pragma unroll
  for (int ci = 0; ci < MR / 64; ++ci) {
    const int m0 = ms * MR + ci * 64;
    const int mtile0 = m0 >> 4;

    // ---- per-mt: K=128 GEMM (W frags direct from L2) + poly quadrature --
#pragma unroll
    for (int mt = 0; mt < 4; ++mt) {
      // ipr, ipiP (z_im*dj_re), ipiN (z_re*dj_im), zd, ad
      float4v acc0 = {0.f, 0.f, 0.f, 0.f}, accP = acc0, accN = acc0,
              acc2 = acc0, acc3 = acc0;
#pragma unroll
      for (int ks = 0; ks < 4; ++ks) {
        const unsigned short* wp =
            wfrag_g + ((size_t)((mtile0 + mt) * 4 + ks)) * 2048 + lane * 8;
        const short8v w1h = *(const short8v*)(wp + 0 * 512);
        const short8v w1l = *(const short8v*)(wp + 1 * 512);
        const short8v w3h = *(const short8v*)(wp + 2 * 512);
        const short8v w3l = *(const short8v*)(wp + 3 * 512);
        const short8v a1h = A1h[ks], a1l = A1l[ks];
        // ipi trick: W2 = [-dj_im; dj_re] is W1 with k-slices swapped and
        // one half negated -> accumulate A1[ks^2] x W1[ks] into accP/accN.
        const short8v s1h = A1h[ks ^ 2], s1l = A1l[ks ^ 2];
        const short8v a2h = A2h[ks], a2l = A2l[ks];
        acc0 = MFMA(a1h, w1h, acc0);
        acc0 = MFMA(a1h, w1l, acc0);
        acc0 = MFMA(a1l, w1h, acc0);
        if (ks < 2) {
          accP = MFMA(s1h, w1h, accP);
          accP = MFMA(s1h, w1l, accP);
          accP = MFMA(s1l, w1h, accP);
        } else {
          accN = MFMA(s1h, w1h, accN);
          accN = MFMA(s1h, w1l, accN);
          accN = MFMA(s1l, w1h, accN);
        }
        acc2 = MFMA(a1h, w3h, acc2);
        acc2 = MFMA(a1h, w3l, acc2);
        acc2 = MFMA(a1l, w3h, acc2);
        acc3 = MFMA(a2h, w1h, acc3);
        acc3 = MFMA(a2h, w1l, acc3);
        acc3 = MFMA(a2l, w1h, acc3);
      }

      // poly quadrature: arg(t) = A2 t^2 + B2 t + C, exp2, alpha folded.
      const int mloc = mt * 16 + (lane & 15);
      const float4 mA = *(const float4*)(mc_g + (size_t)(m0 + mloc) * 8);
      const float4 mB = *(const float4*)(mc_g + (size_t)(m0 + mloc) * 8 + 4);
      const float c1r = mA.x, c1i = mA.y, zj2 = mA.z, Km = mA.w;
      const float A2 = mB.x, B2 = mB.y, nsoL = mB.z, nspmoL = mB.w;
#pragma unroll
      for (int r = 0; r < 4; ++r) {
        const float ipr2 = acc0[r] - c1r;
        const float ipi2 = (accP[r] - accN[r]) - c1i;
        const float q0 = fmaf(-2.f, acc2[r], bz[r]) + zj2;
        const float db = fmaf(fmaf(-2.f, acc3[r], bd[r]), nsoL, Km);
        const float r2 = fmaf(ipr2, ipr2, ipi2 * ipi2);
        const float bq = ipr2 * B2;
        const float cc = fmaf(nspmoL, r2, fmaf(nsoL, q0, db));
        float qacc = 0.f;
#pragma unroll
        for (int kq = 0; kq < 8; ++kq) {
          const float tk = TQ[kq];
          const float arg = fmaf(fmaf(A2, tk, bq), tk, cc);
          qacc = fmaf(WQ[kq], fast_exp2(arg), qacc);
        }
        const int bloc = w * 16 + g * 4 + r;
        wgt_hi[bloc][mloc] = f32_bf16(qacc);
      }
    }

    // ---- That accumulation via MFMA (wgt single-bf16 x tfrag hi/lo);
    // wave-private wgt rows -> in-wave LDS ordering, no barrier ----
    const int mchunk = ms * (MR / 64) + ci;
#pragma unroll
    for (int ks2 = 0; ks2 < 2; ++ks2) {
      const int row = w * 16 + (lane & 15);
      const int colb = ks2 * 32 + g * 4;
      const short4v p0 = *(const short4v*)&wgt_hi[row][colb];
      const short4v p1 = *(const short4v*)&wgt_hi[row][colb + 16];
      const short8v ah = __builtin_shufflevector(p0, p1, 0, 1, 2, 3, 4, 5, 6, 7);
#pragma unroll
      for (int ct = 0; ct < 4; ++ct) {
        const size_t toff =
            ((((size_t)mchunk * 4 + ct) * 2 + ks2) * 2) * 512 + lane * 8;
        const short8v th = *(const short8v*)(tfrag_g + toff);
        const short8v tl = *(const short8v*)(tfrag_g + toff + 512);
        Tacc[ct] = MFMA(ah, th, Tacc[ct]);
        Tacc[ct] = MFMA(ah, tl, Tacc[ct]);
      }
    }
  }

  // partial T for this m-split: D row = 4g + r, col = ct*16+(lane&15).
#pragma unroll
  for (int ct = 0; ct < 4; ++ct)
#pragma unroll
    for (int r = 0; r < 4; ++r)
      part_g[((size_t)ms * B_DIM + (b0 + w * 16 + g * 4 + r)) * S_DIM +
             ct * 16 + (lane & 15)] = Tacc[ct][r];
}

// ------------- reduce partials (float4-vectorized) -----------------------
__global__ __launch_bounds__(256) void reduce_parts(float* __restrict__ out) {
  const int i = blockIdx.x * 256 + threadIdx.x;  // [0, 32768)
  float4 s = {0.f, 0.f, 0.f, 0.f};
#pragma unroll
  for (int p = 0; p < MSPLIT; ++p) {
    const float4 v = *(const float4*)(part_g + (size_t)p * B_DIM * S_DIM + i * 4);
    s.x += v.x;
    s.y += v.y;
    s.z += v.z;
    s.w += v.w;
  }
  *(float4*)(out + (size_t)i * 4) = s;
}

extern "C" void kernel_launch(void* const* d_in, const int* in_sizes, int n_in,
                              void* d_out, int out_size, void* d_ws,
                              size_t ws_size, hipStream_t stream) {
  const float* z_re = (const float*)d_in[0];
  const float* z_im = (const float*)d_in[1];
  const float* d_re = (const float*)d_in[2];
  const float* d_im = (const float*)d_in[3];
  const float* zj_re = (const float*)d_in[4];
  const float* zj_im = (const float*)d_in[5];
  const float* dj_re = (const float*)d_in[6];
  const float* dj_im = (const float*)d_in[7];
  const float* That_re = (const float*)d_in[8];
  const float* alpha = (const float*)d_in[10];
  const float* sig_par = (const float*)d_in[11];
  const float* sig_perp = (const float*)d_in[12];

  build_all<<<dim3(1280 + M_DIM / 4 + B_DIM / 4), dim3(256), 0, stream>>>(
      zj_re, zj_im, dj_re, dj_im, That_re, alpha, sig_par, sig_perp, z_re,
      z_im, d_re, d_im);
  cpsf_mfma<<<dim3((B_DIM / BTILE) * MSPLIT), dim3(256), 0, stream>>>(
      z_re, z_im, d_re, d_im);
  reduce_parts<<<dim3(B_DIM * S_DIM / 1024), dim3(256), 0, stream>>>(
      (float*)d_out);
}